// Round 16
// baseline (621.200 us; speedup 1.0000x reference)
//
#include <hip/hip_runtime.h>
#include <math.h>

// ---------------- problem constants ----------------
#define NDRUG 1000
#define NCELL 1000
#define NGENE 6000
#define NNODE 8000
#define H1 256
#define HD  512
#define E0  160000
#define ET  168000
#define BSZ 10000
#define GKP 6016
#define ZSPLIT 8
#define ZCH 768

typedef __attribute__((ext_vector_type(8))) short bf16x8;
typedef __attribute__((ext_vector_type(4))) float f32x4;

__device__ inline unsigned short f2bf(float f)
{
    unsigned u = __float_as_uint(f);
    u += 0x7fffu + ((u >> 16) & 1u);   // RNE
    return (unsigned short)(u >> 16);
}
__device__ inline float bf2f(unsigned short h)
{
    return __uint_as_float(((unsigned)h) << 16);
}

// ---------------- drug+cell f32 -> (hi,lo) bf16 with padding, one launch ----------------
__global__ void cvt_pad2_dc_kernel(const float* __restrict__ drug, unsigned short* dh, unsigned short* dl,
                                   const float* __restrict__ cell, unsigned short* ch, unsigned short* cl)
{
    const float* in;
    unsigned short *hi, *lo;
    long u0;
    if (blockIdx.x < 512) { in = drug; hi = dh; lo = dl; u0 = (long)blockIdx.x * 256 + threadIdx.x; }
    else                  { in = cell; hi = ch; lo = cl; u0 = (long)(blockIdx.x - 512) * 256 + threadIdx.x; }
    const long total = (long)1024 * 1024 / 8;
    for (long u = u0; u < total; u += 512 * 256) {
        long row = u / 128; int kc = (int)(u % 128);
        unsigned short oh[8], ol[8];
        if (row < 1000 && kc * 8 < 1000) {
            const float* p = in + row * 1000 + kc * 8;
            float4 a = *(const float4*)p, b = *(const float4*)(p + 4);
            float v[8] = {a.x, a.y, a.z, a.w, b.x, b.y, b.z, b.w};
            #pragma unroll
            for (int i = 0; i < 8; ++i) {
                unsigned short h = f2bf(v[i]);
                oh[i] = h;
                ol[i] = f2bf(v[i] - bf2f(h));
            }
        } else {
            #pragma unroll
            for (int i = 0; i < 8; ++i) { oh[i] = 0; ol[i] = 0; }
        }
        *(uint4*)(hi + u * 8) = *(const uint4*)oh;
        *(uint4*)(lo + u * 8) = *(const uint4*)ol;
    }
}

// ---------------- batched W[K][N] -> Wt_{hi,lo}[N][Kp], 5 weights in one launch ----------------
struct TC5 {
    const float* W[5];
    unsigned short* Wh[5];
    unsigned short* Wl[5];
    int K[5]; int N[5]; int Kp[5]; int gx[5];
    int start[6];
};

__global__ __launch_bounds__(256) void transpose_cvt2_batch(TC5 d)
{
    int bid = blockIdx.x;
    int idx = 0;
    #pragma unroll
    for (int i = 1; i < 5; ++i) if (bid >= d.start[i]) idx = i;
    int local = bid - d.start[idx];
    int gx = d.gx[idx];
    int K = d.K[idx], N = d.N[idx], Kp = d.Kp[idx];
    const float* W = d.W[idx];
    unsigned short* Wh = d.Wh[idx];
    unsigned short* Wl = d.Wl[idx];
    __shared__ float t[32][33];
    int kb = (local % gx) * 32, nb = (local / gx) * 32;
    int tx = threadIdx.x & 31, ty = threadIdx.x >> 5;
    #pragma unroll
    for (int i = 0; i < 32; i += 8) {
        int k = kb + ty + i;
        t[ty + i][tx] = (k < K) ? W[(long)k * N + nb + tx] : 0.f;
    }
    __syncthreads();
    #pragma unroll
    for (int i = 0; i < 32; i += 8) {
        int n = nb + ty + i;
        float v = t[tx][ty + i];
        unsigned short h = f2bf(v);
        Wh[(long)n * Kp + kb + tx] = h;
        Wl[(long)n * Kp + kb + tx] = f2bf(v - bf2f(h));
    }
}

// ---------------- split-bf16 MFMA GEMM, 64x64 tile ----------------
template<int OUTBF>
__global__ __launch_bounds__(256) void gemm_mfma2(const unsigned short* __restrict__ Ah,
                                                  const unsigned short* __restrict__ Al,
                                                  const unsigned short* __restrict__ Bh,
                                                  const unsigned short* __restrict__ Bl,
                                                  const float* __restrict__ bias,
                                                  float* __restrict__ Cf,
                                                  unsigned short* __restrict__ Cbh,
                                                  unsigned short* __restrict__ Cbl,
                                                  unsigned short* __restrict__ Cx,
                                                  int M, int Kp, int N)
{
    __shared__ unsigned short AsH[64 * 64];
    __shared__ unsigned short AsL[64 * 64];
    __shared__ unsigned short BsH[64 * 64];
    __shared__ unsigned short BsL[64 * 64];
    char* AsH8 = (char*)AsH; char* AsL8 = (char*)AsL;
    char* BsH8 = (char*)BsH; char* BsL8 = (char*)BsL;
    int tid = threadIdx.x;
    int w = tid >> 6, l = tid & 63;
    int wr = w >> 1, wc = w & 1;
    int g = l >> 4, r16 = l & 15;
    int row0 = blockIdx.y * 64, col0 = blockIdx.x * 64;
    int srow = tid >> 3, skc = tid & 7;
    int B0 = srow * 128 + skc * 16;       int P0 = B0 ^ ((srow & 7) << 4);
    int r1 = srow + 32;                   int B1 = r1 * 128 + skc * 16;
    int P1 = B1 ^ ((r1 & 7) << 4);
    f32x4 acc[2][2] = {};
    for (int k0 = 0; k0 < Kp; k0 += 64) {
        long a0 = (long)(row0 + srow) * Kp + k0 + skc * 8;
        long a1 = (long)(row0 + srow + 32) * Kp + k0 + skc * 8;
        long b0 = (long)(col0 + srow) * Kp + k0 + skc * 8;
        long b1 = (long)(col0 + srow + 32) * Kp + k0 + skc * 8;
        uint4 ah0 = *(const uint4*)(Ah + a0); uint4 ah1 = *(const uint4*)(Ah + a1);
        uint4 al0 = *(const uint4*)(Al + a0); uint4 al1 = *(const uint4*)(Al + a1);
        uint4 bh0 = *(const uint4*)(Bh + b0); uint4 bh1 = *(const uint4*)(Bh + b1);
        uint4 bl0 = *(const uint4*)(Bl + b0); uint4 bl1 = *(const uint4*)(Bl + b1);
        __syncthreads();
        *(uint4*)(AsH8 + P0) = ah0; *(uint4*)(AsH8 + P1) = ah1;
        *(uint4*)(AsL8 + P0) = al0; *(uint4*)(AsL8 + P1) = al1;
        *(uint4*)(BsH8 + P0) = bh0; *(uint4*)(BsH8 + P1) = bh1;
        *(uint4*)(BsL8 + P0) = bl0; *(uint4*)(BsL8 + P1) = bl1;
        __syncthreads();
        #pragma unroll
        for (int kk = 0; kk < 2; ++kk) {
            bf16x8 afh[2], afl[2], bfh[2], bfl[2];
            #pragma unroll
            for (int m = 0; m < 2; ++m) {
                int row = wr * 32 + m * 16 + r16;
                int Bb = (row * 128 + kk * 64 + g * 16) ^ ((row & 7) << 4);
                afh[m] = *(const bf16x8*)(AsH8 + Bb);
                afl[m] = *(const bf16x8*)(AsL8 + Bb);
            }
            #pragma unroll
            for (int n = 0; n < 2; ++n) {
                int row = wc * 32 + n * 16 + r16;
                int Bb = (row * 128 + kk * 64 + g * 16) ^ ((row & 7) << 4);
                bfh[n] = *(const bf16x8*)(BsH8 + Bb);
                bfl[n] = *(const bf16x8*)(BsL8 + Bb);
            }
            #pragma unroll
            for (int m = 0; m < 2; ++m)
                #pragma unroll
                for (int n = 0; n < 2; ++n) {
                    acc[m][n] = __builtin_amdgcn_mfma_f32_16x16x32_bf16(afh[m], bfh[n], acc[m][n], 0, 0, 0);
                    acc[m][n] = __builtin_amdgcn_mfma_f32_16x16x32_bf16(afh[m], bfl[n], acc[m][n], 0, 0, 0);
                    acc[m][n] = __builtin_amdgcn_mfma_f32_16x16x32_bf16(afl[m], bfh[n], acc[m][n], 0, 0, 0);
                }
        }
    }
    #pragma unroll
    for (int m = 0; m < 2; ++m) {
        #pragma unroll
        for (int n = 0; n < 2; ++n) {
            #pragma unroll
            for (int r = 0; r < 4; ++r) {
                int rowg = row0 + wr * 32 + m * 16 + g * 4 + r;
                int colg = col0 + wc * 32 + n * 16 + r16;
                if (rowg < M) {
                    float v = acc[m][n][r] + bias[colg];
                    if (OUTBF) {
                        unsigned short h = f2bf(v);
                        Cbh[(long)rowg * N + colg] = h;
                        Cbl[(long)rowg * N + colg] = f2bf(v - bf2f(h));
                    } else {
                        Cf[(long)rowg * N + colg] = v;
                        Cx[(long)rowg * N + colg] = f2bf(v);
                    }
                }
            }
        }
    }
}

// ---------------- gene GEMM: NO-LDS dataflow. Fragments loaded directly from global. ----------
// A fragment (lane l, subtile m): 8 f32 at row (row0+wr*64+m*16+(l&15)), k = k0+(l>>4)*8 ->
// cvt to hi/lo bf16x8 in registers. B fragment: bf16x8 direct from Wt_{h,l}[col][k].
// No LDS, no barriers; compiler software-pipelines freely.
__global__ __launch_bounds__(256) void gemm_gene_noLDS(const float* __restrict__ A,
                                                       const unsigned short* __restrict__ Bh,
                                                       const unsigned short* __restrict__ Bl,
                                                       float* __restrict__ part)
{
    int tid = threadIdx.x;
    int w = tid >> 6, l = tid & 63;
    int wr = w >> 1, wc = w & 1;
    int g = l >> 4, r16 = l & 15;
    int pid = blockIdx.x;
    int L = (pid & 7) * 94 + (pid >> 3);      // XCD relabel: pairs + z-chunk per XCD
    int xb = L & 1;
    int yb = (L >> 1) % 47;
    int z  = L / 94;
    int row0 = yb * 128, col0 = xb * 128;
    int kbeg = z * ZCH;
    int kend = kbeg + ZCH; if (kend > GKP) kend = GKP;
    int koff = g * 8;
    const float* arp[4];
    bool arok[4];
    #pragma unroll
    for (int m = 0; m < 4; ++m) {
        int r = row0 + wr * 64 + m * 16 + r16;
        arok[m] = (r < NGENE);
        arp[m] = A + (long)r * NGENE;
    }
    const unsigned short* bhp[4];
    const unsigned short* blp[4];
    #pragma unroll
    for (int n = 0; n < 4; ++n) {
        int c = col0 + wc * 64 + n * 16 + r16;
        bhp[n] = Bh + (long)c * GKP;
        blp[n] = Bl + (long)c * GKP;
    }
    f32x4 acc[4][4] = {};
    #pragma unroll 2
    for (int k0 = kbeg; k0 < kend; k0 += 32) {
        int gk = k0 + koff;
        bool kok = (gk + 8 <= NGENE);    // k multiples of 8; 6000%8==0 so no straddle
        bf16x8 afh[4], afl[4], bfh[4], bfl[4];
        #pragma unroll
        for (int m = 0; m < 4; ++m) {
            float4 v0 = make_float4(0.f, 0.f, 0.f, 0.f), v1 = v0;
            if (arok[m] && kok) {
                v0 = *(const float4*)(arp[m] + gk);
                v1 = *(const float4*)(arp[m] + gk + 4);
            }
            float vv[8] = {v0.x, v0.y, v0.z, v0.w, v1.x, v1.y, v1.z, v1.w};
            unsigned short hh[8], ll[8];
            #pragma unroll
            for (int j = 0; j < 8; ++j) {
                unsigned u = __float_as_uint(vv[j]);
                hh[j] = (unsigned short)(u >> 16);                    // truncation hi
                ll[j] = f2bf(vv[j] - __uint_as_float(u & 0xffff0000u)); // exact remainder, RNE
            }
            afh[m] = *(const bf16x8*)hh;
            afl[m] = *(const bf16x8*)ll;
        }
        #pragma unroll
        for (int n = 0; n < 4; ++n) {
            bfh[n] = *(const bf16x8*)(bhp[n] + gk);
            bfl[n] = *(const bf16x8*)(blp[n] + gk);
        }
        #pragma unroll
        for (int m = 0; m < 4; ++m)
            #pragma unroll
            for (int n = 0; n < 4; ++n) {
                acc[m][n] = __builtin_amdgcn_mfma_f32_16x16x32_bf16(afh[m], bfh[n], acc[m][n], 0, 0, 0);
                acc[m][n] = __builtin_amdgcn_mfma_f32_16x16x32_bf16(afh[m], bfl[n], acc[m][n], 0, 0, 0);
                acc[m][n] = __builtin_amdgcn_mfma_f32_16x16x32_bf16(afl[m], bfh[n], acc[m][n], 0, 0, 0);
            }
    }
    #pragma unroll
    for (int m = 0; m < 4; ++m) {
        #pragma unroll
        for (int n = 0; n < 4; ++n) {
            #pragma unroll
            for (int r = 0; r < 4; ++r) {
                int rowg = row0 + wr * 64 + m * 16 + g * 4 + r;
                int colg = col0 + wc * 64 + n * 16 + r16;
                if (rowg < NGENE)
                    part[((long)z * NGENE + rowg) * H1 + colg] = acc[m][n][r];
            }
        }
    }
}

// ---------------- split-K reduce ----------------
__global__ __launch_bounds__(256) void reduce_splitk_kernel(const float* __restrict__ part,
                                                            const float* __restrict__ bias,
                                                            unsigned short* __restrict__ xh,
                                                            unsigned short* __restrict__ xl)
{
    const long NEL = (long)NGENE * H1;
    long stride = (long)gridDim.x * blockDim.x;
    for (long q = (long)blockIdx.x * blockDim.x + threadIdx.x; q * 4 < NEL; q += stride) {
        long e = q * 4;
        float4 sv = *(const float4*)(part + e);
        #pragma unroll
        for (int z = 1; z < ZSPLIT; ++z) {
            float4 t = *(const float4*)(part + (long)z * NEL + e);
            sv.x += t.x; sv.y += t.y; sv.z += t.z; sv.w += t.w;
        }
        int col = (int)(e & (H1 - 1));
        float4 b = *(const float4*)(bias + col);
        float v[4] = {sv.x + b.x, sv.y + b.y, sv.z + b.z, sv.w + b.w};
        unsigned short oh[4], ol[4];
        #pragma unroll
        for (int i = 0; i < 4; ++i) {
            oh[i] = f2bf(v[i]);
            ol[i] = f2bf(v[i] - bf2f(oh[i]));
        }
        long o = (long)(NDRUG + NCELL) * H1 + e;
        *(uint2*)(xh + o) = *(const uint2*)oh;
        *(uint2*)(xl + o) = *(const uint2*)ol;
    }
}

// ---------------- init kernels ----------------
__global__ void init1_kernel(float* m, int* deg, float* colstats, float* scal)
{
    int i = blockIdx.x * 256 + threadIdx.x;
    if (i < NNODE * 4) m[i] = -3.402823466e38f;
    if (i < NNODE) deg[i] = 0;
    if (i < 1024) colstats[i] = 0.f;
    if (i < 8) scal[i] = 0.f;
}

__global__ void init2_kernel(float* m, float* colstats)
{
    int i = blockIdx.x * 256 + threadIdx.x;
    if (i < NNODE * 4) m[i] = -3.402823466e38f;
    if (i < 1024) colstats[i] = 0.f;
}

// ---------------- fused: sum(edge_attr)->scal[0] + ce ----------------
__global__ __launch_bounds__(512) void small_pre_kernel(const float* __restrict__ eattr, float* scal,
                                                        const float* We1, const float* ae1,
                                                        const float* We2, const float* ae2, float* ce)
{
    if (blockIdx.x < 64) {
        float s = 0.f;
        for (int i = blockIdx.x * 512 + threadIdx.x; i < E0; i += 64 * 512)
            s += eattr[i];
        for (int off = 32; off; off >>= 1) s += __shfl_down(s, off);
        if ((threadIdx.x & 63) == 0) atomicAdd(&scal[0], s);
    } else {
        __shared__ float sm[512];
        int t = threadIdx.x;
        sm[t] = We1[t] * ae1[t];
        __syncthreads();
        if (t < 4) { float s = 0.f; for (int c = 0; c < 128; ++c) s += sm[t * 128 + c]; ce[t] = s; }
        __syncthreads();
        sm[t] = We2[t] * ae2[t];
        __syncthreads();
        if (t < 4) { float s = 0.f; for (int c = 0; c < 128; ++c) s += sm[t * 128 + c]; ce[4 + t] = s; }
    }
}

// ---------------- degree histogram ----------------
__global__ void deg_kernel(const int* __restrict__ ei, int* __restrict__ deg)
{
    int e = blockIdx.x * blockDim.x + threadIdx.x;
    if (e >= ET) return;
    int d = (e < E0) ? ei[E0 + e] : (e - E0);
    atomicAdd(&deg[d], 1);
}

// ---------------- exclusive scan ----------------
__global__ __launch_bounds__(1024) void scan_kernel(const int* __restrict__ deg,
                                                    int* __restrict__ row_start,
                                                    int* __restrict__ cursor)
{
    __shared__ int sm[1024];
    int t = threadIdx.x;
    int base = t * 8;
    int loc[8];
    int sum = 0;
    #pragma unroll
    for (int j = 0; j < 8; ++j) {
        int v = (base + j < NNODE) ? deg[base + j] : 0;
        loc[j] = sum; sum += v;
    }
    sm[t] = sum;
    __syncthreads();
    for (int off = 1; off < 1024; off <<= 1) {
        int v = (t >= off) ? sm[t - off] : 0;
        __syncthreads();
        sm[t] += v;
        __syncthreads();
    }
    int excl = sm[t] - sum;
    #pragma unroll
    for (int j = 0; j < 8; ++j) {
        int idx = base + j;
        if (idx < NNODE) { int v = excl + loc[j]; row_start[idx] = v; cursor[idx] = v; }
    }
    if (t == 1023) row_start[NNODE] = sm[1023];
}

// ---------------- scatter edge structure into CSR ----------------
__global__ void scatter_csr_kernel(const int* __restrict__ ei, int* __restrict__ cursor,
                                   int* __restrict__ csr_src, int* __restrict__ pos_of_e)
{
    int e = blockIdx.x * blockDim.x + threadIdx.x;
    if (e >= ET) return;
    int s, d;
    if (e < E0) { s = ei[e]; d = ei[E0 + e]; }
    else        { s = d = e - E0; }
    int pos = atomicAdd(&cursor[d], 1);
    csr_src[pos] = s;
    pos_of_e[e] = pos;
}

// ---------------- per-node attention coefficients (4 nodes per block) ----------------
__global__ __launch_bounds__(256) void attn_coef_kernel(const float* __restrict__ xw,
                                                        const float* __restrict__ as,
                                                        const float* __restrict__ ad,
                                                        float* __restrict__ a_src,
                                                        float* __restrict__ a_dst)
{
    int n = blockIdx.x * 4 + (threadIdx.x >> 6);
    int l = threadIdx.x & 63;
    #pragma unroll
    for (int h = 0; h < 4; ++h) {
        float x1 = xw[(long)n * HD + h * 128 + l];
        float x2 = xw[(long)n * HD + h * 128 + 64 + l];
        float s = x1 * as[h * 128 + l] + x2 * as[h * 128 + 64 + l];
        float d = x1 * ad[h * 128 + l] + x2 * ad[h * 128 + 64 + l];
        for (int off = 32; off; off >>= 1) { s += __shfl_down(s, off); d += __shfl_down(d, off); }
        if (l == 0) { a_src[n * 4 + h] = s; a_dst[n * 4 + h] = d; }
    }
}

// ---------------- atomic float max ----------------
__device__ inline void atomicMaxF(float* addr, float v)
{
    if (v >= 0.f) atomicMax((int*)addr, __float_as_int(v));
    else          atomicMin((unsigned int*)addr, __float_as_uint(v));
}

// ---------------- per-edge alpha (scatter to CSR order) + segment max ----------------
__global__ void alpha_max_kernel(const int* __restrict__ ei, const float* __restrict__ eattr,
                                 const float* __restrict__ scal,
                                 const float* __restrict__ a_src, const float* __restrict__ a_dst,
                                 const float* __restrict__ ce,
                                 float* __restrict__ csr_alpha,
                                 const int* __restrict__ pos_of_e,
                                 float* __restrict__ m)
{
    int e = blockIdx.x * blockDim.x + threadIdx.x;
    if (e >= ET) return;
    int s, d; float a;
    if (e < E0) { s = ei[e]; d = ei[E0 + e]; a = eattr[e]; }
    else        { s = d = e - E0; a = scal[0] * (1.0f / E0); }
    float4 av;
    float* avp = (float*)&av;
    #pragma unroll
    for (int h = 0; h < 4; ++h) {
        float v = a_src[s * 4 + h] + a_dst[d * 4 + h] + a * ce[h];
        v = v > 0.f ? v : 0.2f * v;
        avp[h] = v;
        atomicMaxF(&m[d * 4 + h], v);
    }
    *(float4*)(csr_alpha + (long)pos_of_e[e] * 4) = av;
}

// ---------------- aggregation ----------------
__global__ __launch_bounds__(256) void aggregate_kernel(const unsigned short* __restrict__ xwb,
                                                        const float* __restrict__ csr_alpha,
                                                        const float* __restrict__ m,
                                                        const int* __restrict__ rs,
                                                        const int* __restrict__ csr_src,
                                                        const float* __restrict__ bias,
                                                        float* __restrict__ out)
{
    int n = blockIdx.x;
    int h = threadIdx.x >> 6;
    int l = threadIdx.x & 63;
    float mnh = m[n * 4 + h];
    int i0 = rs[n], i1 = rs[n + 1];
    float den = 0.f;
    for (int i = i0 + l; i < i1; i += 64)
        den += expf(csr_alpha[(long)i * 4 + h] - mnh);
    for (int off = 32; off; off >>= 1) den += __shfl_down(den, off);
    den = __shfl(den, 0);
    float rden = 1.0f / (den + 1e-16f);
    float acc0 = 0.f, acc1 = 0.f;
    int i = i0;
    for (; i + 7 < i1; i += 8) {
        int      sv[8];
        float    av[8];
        unsigned xv[8];
        #pragma unroll
        for (int j = 0; j < 8; ++j) {
            sv[j] = csr_src[i + j];
            av[j] = csr_alpha[(long)(i + j) * 4 + h];
        }
        #pragma unroll
        for (int j = 0; j < 8; ++j)
            xv[j] = *(const unsigned*)(xwb + (long)sv[j] * HD + h * 128 + 2 * l);
        #pragma unroll
        for (int j = 0; j < 8; ++j) {
            float w = expf(av[j] - mnh);
            acc0 += w * bf2f((unsigned short)(xv[j] & 0xffffu));
            acc1 += w * bf2f((unsigned short)(xv[j] >> 16));
        }
    }
    for (; i < i1; ++i) {
        int s = csr_src[i];
        float w = expf(csr_alpha[(long)i * 4 + h] - mnh);
        unsigned x = *(const unsigned*)(xwb + (long)s * HD + h * 128 + 2 * l);
        acc0 += w * bf2f((unsigned short)(x & 0xffffu));
        acc1 += w * bf2f((unsigned short)(x >> 16));
    }
    float2 o;
    o.x = acc0 * rden + bias[h * 128 + 2 * l];
    o.y = acc1 * rden + bias[h * 128 + 2 * l + 1];
    *(float2*)(out + (long)n * HD + h * 128 + 2 * l) = o;
}

// ---------------- graph norm: fused column sum + sum-of-squares ----------------
__global__ __launch_bounds__(256) void colstats_kernel(const float* __restrict__ x,
                                                       float* __restrict__ colsum,
                                                       float* __restrict__ colsumsq)
{
    int t = threadIdx.x, b = blockIdx.x;
    float s0 = 0.f, s1 = 0.f, q0 = 0.f, q1 = 0.f;
    for (int r = b * 125; r < (b + 1) * 125; ++r) {
        float v0 = x[(long)r * HD + t];
        float v1 = x[(long)r * HD + t + 256];
        s0 += v0; q0 += v0 * v0;
        s1 += v1; q1 += v1 * v1;
    }
    atomicAdd(&colsum[t], s0);
    atomicAdd(&colsum[t + 256], s1);
    atomicAdd(&colsumsq[t], q0);
    atomicAdd(&colsumsq[t + 256], q1);
}

// norm (+ReLU) in place; writes hi/lo bf16 copies
__global__ void norm_kernel(float* __restrict__ x,
                            unsigned short* __restrict__ xbh, unsigned short* __restrict__ xbl,
                            const float* __restrict__ colsum,
                            const float* __restrict__ colsumsq,
                            const float* __restrict__ g, const float* __restrict__ be,
                            const float* __restrict__ ms)
{
    int stride = gridDim.x * blockDim.x;
    for (int idx = blockIdx.x * blockDim.x + threadIdx.x; idx < NNODE * HD; idx += stride) {
        int j = idx & 511;
        float mu  = colsum[j] * (1.0f / NNODE);
        float ex2 = colsumsq[j] * (1.0f / NNODE);
        float msj = ms[j];
        float var = ex2 - msj * (2.0f - msj) * mu * mu;
        float v = x[idx] - msj * mu;
        float y = g[j] * v / sqrtf(var + 1e-5f) + be[j];
        y = y > 0.f ? y : 0.f;
        x[idx] = y;
        unsigned short h = f2bf(y);
        xbh[idx] = h;
        xbl[idx] = f2bf(y - bf2f(h));
    }
}

// ---------------- prediction head ----------------
__global__ __launch_bounds__(256) void head_kernel(const float* __restrict__ x2,
                                                   const int* __restrict__ idd,
                                                   const int* __restrict__ idc,
                                                   const float* __restrict__ Wout,
                                                   const float* __restrict__ bout,
                                                   float* __restrict__ out0)
{
    int w = threadIdx.x >> 6, l = threadIdx.x & 63;
    int b = blockIdx.x * 4 + w;
    if (b >= BSZ) return;
    int rd = idd[b], rc = idc[b];
    float s = 0.f;
    #pragma unroll
    for (int k = l; k < HD; k += 64)
        s += x2[(long)rd * HD + k] * Wout[k] + x2[(long)rc * HD + k] * Wout[HD + k];
    for (int off = 32; off; off >>= 1) s += __shfl_down(s, off);
    if (l == 0) out0[b] = s + bout[0];
}

// ---------------- all_att: zero + scatter scalar ----------------
__global__ void zero_f4_kernel(float4* __restrict__ p, long n4)
{
    long stride = (long)gridDim.x * blockDim.x;
    for (long i = (long)blockIdx.x * blockDim.x + threadIdx.x; i < n4; i += stride)
        p[i] = make_float4(0.f, 0.f, 0.f, 0.f);
}

__global__ void scatter_att_kernel(const int* __restrict__ ei, float* __restrict__ attm)
{
    int e = blockIdx.x * blockDim.x + threadIdx.x;
    if (e >= ET) return;
    int s, d;
    if (e < E0) { s = ei[e]; d = ei[E0 + e]; }
    else        { s = d = e - E0; }
    const float val = 2.0f * (float)NNODE / (float)ET;
    attm[(long)s * NNODE + d] = val;
}

// ---------------- launch ----------------
extern "C" void kernel_launch(void* const* d_in, const int* in_sizes, int n_in,
                              void* d_out, int out_size, void* d_ws, size_t ws_size,
                              hipStream_t stream)
{
    const float* drug   = (const float*)d_in[0];
    const float* cell   = (const float*)d_in[1];
    const float* gene   = (const float*)d_in[2];
    const float* eattr  = (const float*)d_in[3];
    const int*   ei     = (const int*)d_in[4];
    const int*   idd    = (const int*)d_in[5];
    const int*   idc    = (const int*)d_in[6];
    const float* Wdrug  = (const float*)d_in[7];
    const float* bdrug  = (const float*)d_in[8];
    const float* Wcell  = (const float*)d_in[9];
    const float* bcell  = (const float*)d_in[10];
    const float* Wgene  = (const float*)d_in[11];
    const float* bgene  = (const float*)d_in[12];
    const float* W1     = (const float*)d_in[13];
    const float* b1     = (const float*)d_in[14];
    const float* as1    = (const float*)d_in[15];
    const float* ad1    = (const float*)d_in[16];
    const float* We1    = (const float*)d_in[17];
    const float* ae1    = (const float*)d_in[18];
    const float* bias1  = (const float*)d_in[19];
    const float* g1     = (const float*)d_in[20];
    const float* be1    = (const float*)d_in[21];
    const float* ms1    = (const float*)d_in[22];
    const float* W2     = (const float*)d_in[23];
    const float* b2     = (const float*)d_in[24];
    const float* as2    = (const float*)d_in[25];
    const float* ad2    = (const float*)d_in[26];
    const float* We2    = (const float*)d_in[27];
    const float* ae2    = (const float*)d_in[28];
    const float* bias2  = (const float*)d_in[29];
    const float* g2     = (const float*)d_in[30];
    const float* be2    = (const float*)d_in[31];
    const float* ms2    = (const float*)d_in[32];
    const float* Wout   = (const float*)d_in[33];
    const float* bout   = (const float*)d_in[34];

    float* out0 = (float*)d_out;                 // [10000]
    float* attm = (float*)d_out + BSZ;           // [8000*8000]

    // ---- workspace layout ----
    float* ws     = (float*)d_ws;
    float* xw     = ws;                          // 8000*512
    float* outb   = xw + (long)NNODE * HD;       // 8000*512
    float* csr_al = outb + (long)NNODE * HD;     // 168000*4
    float* a_src  = csr_al + (long)ET * 4;       // 32000
    float* a_dst  = a_src + NNODE * 4;           // 32000
    float* mbuf   = a_dst + NNODE * 4;           // 32000
    float* colsum = mbuf + NNODE * 4;            // 512
    float* colsq  = colsum + 512;                // 512
    float* ce     = colsq + 512;                 // 8
    float* scal   = ce + 8;                      // 8
    int* deg      = (int*)(scal + 8);            // 8000
    int* rs       = deg + NNODE;                 // 8004
    int* cursor   = rs + NNODE + 4;              // 8000
    int* csr_src  = cursor + NNODE;              // 168000
    int* pos_of_e = csr_src + ET;                // 168000
    unsigned short* p = (unsigned short*)(pos_of_e + ET);
    unsigned short* xwb    = p; p += (long)NNODE * HD;
    unsigned short* drug_h = p; p += (long)1024 * 1024;
    unsigned short* drug_l = p; p += (long)1024 * 1024;
    unsigned short* cell_h = p; p += (long)1024 * 1024;
    unsigned short* cell_l = p; p += (long)1024 * 1024;
    unsigned short* x0_h   = p; p += (long)NNODE * H1;
    unsigned short* x0_l   = p; p += (long)NNODE * H1;
    unsigned short* xb_h   = p; p += (long)NNODE * HD;
    unsigned short* xb_l   = p; p += (long)NNODE * HD;
    unsigned short* Wd_h   = p; p += 256 * 1024;
    unsigned short* Wd_l   = p; p += 256 * 1024;
    unsigned short* Wc_h   = p; p += 256 * 1024;
    unsigned short* Wc_l   = p; p += 256 * 1024;
    unsigned short* Wg_h   = p; p += 256 * GKP;
    unsigned short* Wg_l   = p; p += 256 * GKP;
    unsigned short* W1_h   = p; p += 512 * 256;
    unsigned short* W1_l   = p; p += 512 * 256;
    unsigned short* W2_h   = p; p += 512 * 512;
    unsigned short* W2_l   = p; p += 512 * 512;
    float* partsk = (float*)((((unsigned long long)p) + 15) & ~15ULL);

    dim3 blk256(256);
    int gE = (ET + 255) / 256;

    // init + CSR build + small precomputes
    init1_kernel<<<125, blk256, 0, stream>>>(mbuf, deg, colsum, scal);
    deg_kernel<<<gE, blk256, 0, stream>>>(ei, deg);
    scan_kernel<<<1, 1024, 0, stream>>>(deg, rs, cursor);
    scatter_csr_kernel<<<gE, blk256, 0, stream>>>(ei, cursor, csr_src, pos_of_e);
    small_pre_kernel<<<65, 512, 0, stream>>>(eattr, scal, We1, ae1, We2, ae2, ce);

    // ---- conversions ----
    cvt_pad2_dc_kernel<<<1024, blk256, 0, stream>>>(drug, drug_h, drug_l, cell, cell_h, cell_l);
    {
        TC5 d;
        d.W[0] = Wdrug; d.Wh[0] = Wd_h; d.Wl[0] = Wd_l; d.K[0] = NDRUG; d.N[0] = H1; d.Kp[0] = 1024; d.gx[0] = 32;
        d.W[1] = Wcell; d.Wh[1] = Wc_h; d.Wl[1] = Wc_l; d.K[1] = NCELL; d.N[1] = H1; d.Kp[1] = 1024; d.gx[1] = 32;
        d.W[2] = Wgene; d.Wh[2] = Wg_h; d.Wl[2] = Wg_l; d.K[2] = NGENE; d.N[2] = H1; d.Kp[2] = GKP;  d.gx[2] = 188;
        d.W[3] = W1;    d.Wh[3] = W1_h; d.Wl[3] = W1_l; d.K[3] = H1;    d.N[3] = HD; d.Kp[3] = H1;   d.gx[3] = 8;
        d.W[4] = W2;    d.Wh[4] = W2_h; d.Wl[4] = W2_l; d.K[4] = HD;    d.N[4] = HD; d.Kp[4] = HD;   d.gx[4] = 16;
        d.start[0] = 0;    d.start[1] = 256;  d.start[2] = 512;
        d.start[3] = 2016; d.start[4] = 2144; d.start[5] = 2400;
        transpose_cvt2_batch<<<2400, blk256, 0, stream>>>(d);
    }

    // ---- input projections -> x0 (hi/lo bf16) ----
    gemm_mfma2<1><<<dim3(H1 / 64, 16), blk256, 0, stream>>>(drug_h, drug_l, Wd_h, Wd_l, bdrug,
        nullptr, x0_h, x0_l, nullptr, NDRUG, 1024, H1);
    gemm_mfma2<1><<<dim3(H1 / 64, 16), blk256, 0, stream>>>(cell_h, cell_l, Wc_h, Wc_l, bcell,
        nullptr, x0_h + (long)NDRUG * H1, x0_l + (long)NDRUG * H1, nullptr, NCELL, 1024, H1);
    gemm_gene_noLDS<<<752, blk256, 0, stream>>>(gene, Wg_h, Wg_l, partsk);
    reduce_splitk_kernel<<<1500, blk256, 0, stream>>>(partsk, bgene, x0_h, x0_l);

    // ---- layer 1 ----
    gemm_mfma2<0><<<dim3(HD / 64, NNODE / 64), blk256, 0, stream>>>(x0_h, x0_l, W1_h, W1_l, b1,
        xw, nullptr, nullptr, xwb, NNODE, H1, HD);
    attn_coef_kernel<<<NNODE / 4, blk256, 0, stream>>>(xw, as1, ad1, a_src, a_dst);
    alpha_max_kernel<<<gE, blk256, 0, stream>>>(ei, eattr, scal, a_src, a_dst, ce,
        csr_al, pos_of_e, mbuf);
    aggregate_kernel<<<NNODE, blk256, 0, stream>>>(xwb, csr_al, mbuf, rs, csr_src, bias1, outb);
    colstats_kernel<<<64, blk256, 0, stream>>>(outb, colsum, colsq);
    norm_kernel<<<2048, blk256, 0, stream>>>(outb, xb_h, xb_l, colsum, colsq, g1, be1, ms1);

    // ---- layer 2 ----
    gemm_mfma2<0><<<dim3(HD / 64, NNODE / 64), blk256, 0, stream>>>(xb_h, xb_l, W2_h, W2_l, b2,
        xw, nullptr, nullptr, xwb, NNODE, HD, HD);
    attn_coef_kernel<<<NNODE / 4, blk256, 0, stream>>>(xw, as2, ad2, a_src, a_dst);
    init2_kernel<<<125, blk256, 0, stream>>>(mbuf, colsum);
    alpha_max_kernel<<<gE, blk256, 0, stream>>>(ei, eattr, scal, a_src, a_dst, ce + 4,
        csr_al, pos_of_e, mbuf);
    aggregate_kernel<<<NNODE, blk256, 0, stream>>>(xwb, csr_al, mbuf, rs, csr_src, bias2, outb);
    colstats_kernel<<<64, blk256, 0, stream>>>(outb, colsum, colsq);
    norm_kernel<<<2048, blk256, 0, stream>>>(outb, xb_h, xb_l, colsum, colsq, g2, be2, ms2);

    // ---- head + attention matrix ----
    head_kernel<<<(BSZ + 3) / 4, blk256, 0, stream>>>(outb, idd, idc, Wout, bout, out0);
    zero_f4_kernel<<<2048, blk256, 0, stream>>>((float4*)attm, (long)NNODE * NNODE / 4);
    scatter_att_kernel<<<gE, blk256, 0, stream>>>(ei, attm);
}

// Round 17
// 530.970 us; speedup vs baseline: 1.1699x; 1.1699x over previous
//
#include <hip/hip_runtime.h>
#include <math.h>

// ---------------- problem constants ----------------
#define NDRUG 1000
#define NCELL 1000
#define NGENE 6000
#define NNODE 8000
#define H1 256
#define HD  512
#define E0  160000
#define ET  168000
#define BSZ 10000
#define GKP 6016
#define ZSPLIT 8
#define ZCH 768

typedef __attribute__((ext_vector_type(8))) short bf16x8;
typedef __attribute__((ext_vector_type(4))) float f32x4;

__device__ inline unsigned short f2bf(float f)
{
    unsigned u = __float_as_uint(f);
    u += 0x7fffu + ((u >> 16) & 1u);   // RNE
    return (unsigned short)(u >> 16);
}
__device__ inline float bf2f(unsigned short h)
{
    return __uint_as_float(((unsigned)h) << 16);
}

// ---------------- drug+cell f32 -> (hi,lo) bf16 with padding, one launch ----------------
__global__ void cvt_pad2_dc_kernel(const float* __restrict__ drug, unsigned short* dh, unsigned short* dl,
                                   const float* __restrict__ cell, unsigned short* ch, unsigned short* cl)
{
    const float* in;
    unsigned short *hi, *lo;
    long u0;
    if (blockIdx.x < 512) { in = drug; hi = dh; lo = dl; u0 = (long)blockIdx.x * 256 + threadIdx.x; }
    else                  { in = cell; hi = ch; lo = cl; u0 = (long)(blockIdx.x - 512) * 256 + threadIdx.x; }
    const long total = (long)1024 * 1024 / 8;
    for (long u = u0; u < total; u += 512 * 256) {
        long row = u / 128; int kc = (int)(u % 128);
        unsigned short oh[8], ol[8];
        if (row < 1000 && kc * 8 < 1000) {
            const float* p = in + row * 1000 + kc * 8;
            float4 a = *(const float4*)p, b = *(const float4*)(p + 4);
            float v[8] = {a.x, a.y, a.z, a.w, b.x, b.y, b.z, b.w};
            #pragma unroll
            for (int i = 0; i < 8; ++i) {
                unsigned short h = f2bf(v[i]);
                oh[i] = h;
                ol[i] = f2bf(v[i] - bf2f(h));
            }
        } else {
            #pragma unroll
            for (int i = 0; i < 8; ++i) { oh[i] = 0; ol[i] = 0; }
        }
        *(uint4*)(hi + u * 8) = *(const uint4*)oh;
        *(uint4*)(lo + u * 8) = *(const uint4*)ol;
    }
}

// ---------------- batched W[K][N] -> Wt_{hi,lo}[N][Kp], 5 weights in one launch ----------------
struct TC5 {
    const float* W[5];
    unsigned short* Wh[5];
    unsigned short* Wl[5];
    int K[5]; int N[5]; int Kp[5]; int gx[5];
    int start[6];
};

__global__ __launch_bounds__(256) void transpose_cvt2_batch(TC5 d)
{
    int bid = blockIdx.x;
    int idx = 0;
    #pragma unroll
    for (int i = 1; i < 5; ++i) if (bid >= d.start[i]) idx = i;
    int local = bid - d.start[idx];
    int gx = d.gx[idx];
    int K = d.K[idx], N = d.N[idx], Kp = d.Kp[idx];
    const float* W = d.W[idx];
    unsigned short* Wh = d.Wh[idx];
    unsigned short* Wl = d.Wl[idx];
    __shared__ float t[32][33];
    int kb = (local % gx) * 32, nb = (local / gx) * 32;
    int tx = threadIdx.x & 31, ty = threadIdx.x >> 5;
    #pragma unroll
    for (int i = 0; i < 32; i += 8) {
        int k = kb + ty + i;
        t[ty + i][tx] = (k < K) ? W[(long)k * N + nb + tx] : 0.f;
    }
    __syncthreads();
    #pragma unroll
    for (int i = 0; i < 32; i += 8) {
        int n = nb + ty + i;
        float v = t[tx][ty + i];
        unsigned short h = f2bf(v);
        Wh[(long)n * Kp + kb + tx] = h;
        Wl[(long)n * Kp + kb + tx] = f2bf(v - bf2f(h));
    }
}

// ---------------- split-bf16 MFMA GEMM, 64x64 tile ----------------
template<int OUTBF>
__global__ __launch_bounds__(256) void gemm_mfma2(const unsigned short* __restrict__ Ah,
                                                  const unsigned short* __restrict__ Al,
                                                  const unsigned short* __restrict__ Bh,
                                                  const unsigned short* __restrict__ Bl,
                                                  const float* __restrict__ bias,
                                                  float* __restrict__ Cf,
                                                  unsigned short* __restrict__ Cbh,
                                                  unsigned short* __restrict__ Cbl,
                                                  unsigned short* __restrict__ Cx,
                                                  int M, int Kp, int N)
{
    __shared__ unsigned short AsH[64 * 64];
    __shared__ unsigned short AsL[64 * 64];
    __shared__ unsigned short BsH[64 * 64];
    __shared__ unsigned short BsL[64 * 64];
    char* AsH8 = (char*)AsH; char* AsL8 = (char*)AsL;
    char* BsH8 = (char*)BsH; char* BsL8 = (char*)BsL;
    int tid = threadIdx.x;
    int w = tid >> 6, l = tid & 63;
    int wr = w >> 1, wc = w & 1;
    int g = l >> 4, r16 = l & 15;
    int row0 = blockIdx.y * 64, col0 = blockIdx.x * 64;
    int srow = tid >> 3, skc = tid & 7;
    int B0 = srow * 128 + skc * 16;       int P0 = B0 ^ ((srow & 7) << 4);
    int r1 = srow + 32;                   int B1 = r1 * 128 + skc * 16;
    int P1 = B1 ^ ((r1 & 7) << 4);
    f32x4 acc[2][2] = {};
    for (int k0 = 0; k0 < Kp; k0 += 64) {
        long a0 = (long)(row0 + srow) * Kp + k0 + skc * 8;
        long a1 = (long)(row0 + srow + 32) * Kp + k0 + skc * 8;
        long b0 = (long)(col0 + srow) * Kp + k0 + skc * 8;
        long b1 = (long)(col0 + srow + 32) * Kp + k0 + skc * 8;
        uint4 ah0 = *(const uint4*)(Ah + a0); uint4 ah1 = *(const uint4*)(Ah + a1);
        uint4 al0 = *(const uint4*)(Al + a0); uint4 al1 = *(const uint4*)(Al + a1);
        uint4 bh0 = *(const uint4*)(Bh + b0); uint4 bh1 = *(const uint4*)(Bh + b1);
        uint4 bl0 = *(const uint4*)(Bl + b0); uint4 bl1 = *(const uint4*)(Bl + b1);
        __syncthreads();
        *(uint4*)(AsH8 + P0) = ah0; *(uint4*)(AsH8 + P1) = ah1;
        *(uint4*)(AsL8 + P0) = al0; *(uint4*)(AsL8 + P1) = al1;
        *(uint4*)(BsH8 + P0) = bh0; *(uint4*)(BsH8 + P1) = bh1;
        *(uint4*)(BsL8 + P0) = bl0; *(uint4*)(BsL8 + P1) = bl1;
        __syncthreads();
        #pragma unroll
        for (int kk = 0; kk < 2; ++kk) {
            bf16x8 afh[2], afl[2], bfh[2], bfl[2];
            #pragma unroll
            for (int m = 0; m < 2; ++m) {
                int row = wr * 32 + m * 16 + r16;
                int Bb = (row * 128 + kk * 64 + g * 16) ^ ((row & 7) << 4);
                afh[m] = *(const bf16x8*)(AsH8 + Bb);
                afl[m] = *(const bf16x8*)(AsL8 + Bb);
            }
            #pragma unroll
            for (int n = 0; n < 2; ++n) {
                int row = wc * 32 + n * 16 + r16;
                int Bb = (row * 128 + kk * 64 + g * 16) ^ ((row & 7) << 4);
                bfh[n] = *(const bf16x8*)(BsH8 + Bb);
                bfl[n] = *(const bf16x8*)(BsL8 + Bb);
            }
            #pragma unroll
            for (int m = 0; m < 2; ++m)
                #pragma unroll
                for (int n = 0; n < 2; ++n) {
                    acc[m][n] = __builtin_amdgcn_mfma_f32_16x16x32_bf16(afh[m], bfh[n], acc[m][n], 0, 0, 0);
                    acc[m][n] = __builtin_amdgcn_mfma_f32_16x16x32_bf16(afh[m], bfl[n], acc[m][n], 0, 0, 0);
                    acc[m][n] = __builtin_amdgcn_mfma_f32_16x16x32_bf16(afl[m], bfh[n], acc[m][n], 0, 0, 0);
                }
        }
    }
    #pragma unroll
    for (int m = 0; m < 2; ++m) {
        #pragma unroll
        for (int n = 0; n < 2; ++n) {
            #pragma unroll
            for (int r = 0; r < 4; ++r) {
                int rowg = row0 + wr * 32 + m * 16 + g * 4 + r;
                int colg = col0 + wc * 32 + n * 16 + r16;
                if (rowg < M) {
                    float v = acc[m][n][r] + bias[colg];
                    if (OUTBF) {
                        unsigned short h = f2bf(v);
                        Cbh[(long)rowg * N + colg] = h;
                        Cbl[(long)rowg * N + colg] = f2bf(v - bf2f(h));
                    } else {
                        Cf[(long)rowg * N + colg] = v;
                        Cx[(long)rowg * N + colg] = f2bf(v);
                    }
                }
            }
        }
    }
}

// ---------------- gene GEMM: f32 A, ping-pong double buffer, ONE barrier/iter (r15 version) ----
__global__ __launch_bounds__(256) void gemm_gene_f32(const float* __restrict__ A,
                                                     const unsigned short* __restrict__ Bh,
                                                     const unsigned short* __restrict__ Bl,
                                                     float* __restrict__ part)
{
    __shared__ char lds[65536];   // 2 bufs x {AsH,AsL,BsH,BsL} x 8KB
    int tid = threadIdx.x;
    int w = tid >> 6, l = tid & 63;
    int wr = w >> 1, wc = w & 1;
    int g = l >> 4, r16 = l & 15;
    int pid = blockIdx.x;
    int L = (pid & 7) * 94 + (pid >> 3);
    int xb = L & 1;
    int yb = (L >> 1) % 47;
    int z  = L / 94;
    int row0 = yb * 128, col0 = xb * 128;
    int kbeg = z * ZCH;
    int kend = kbeg + ZCH; if (kend > GKP) kend = GKP;
    int niter = (kend - kbeg) >> 5;
    int arow = tid >> 1, akp = (tid & 1) * 16;
    int t_ar = (arow + (arow >> 2)) & 3;
    int s0 = akp >> 3;
    int wo0 = arow * 64 + ((s0 ^ t_ar) << 4);
    int wo1 = arow * 64 + (((s0 + 1) ^ t_ar) << 4);
    int tA = (r16 + (r16 >> 2)) & 3;
    int soA = (g ^ tA) << 4;
    int gr = row0 + arow;
    const float* arowp = A + (long)gr * NGENE;
    const unsigned short* bhp = Bh + (long)(col0 + arow) * GKP;
    const unsigned short* blp = Bl + (long)(col0 + arow) * GKP;
    bool arok = (gr < NGENE);
    f32x4 acc[4][4] = {};

    float av[16];
    uint4 rbh0, rbh1, rbl0, rbl1;
    {
        int gk = kbeg + akp;
        #pragma unroll
        for (int j = 0; j < 16; j += 4) {
            float4 v = (arok && gk + j < NGENE) ? *(const float4*)(arowp + gk + j)
                                                : make_float4(0.f, 0.f, 0.f, 0.f);
            av[j] = v.x; av[j + 1] = v.y; av[j + 2] = v.z; av[j + 3] = v.w;
        }
        rbh0 = *(const uint4*)(bhp + gk); rbh1 = *(const uint4*)(bhp + gk + 8);
        rbl0 = *(const uint4*)(blp + gk); rbl1 = *(const uint4*)(blp + gk + 8);
    }
    {
        unsigned short ah[16], alr[16];
        #pragma unroll
        for (int j = 0; j < 16; ++j) {
            unsigned u = __float_as_uint(av[j]);
            ah[j] = (unsigned short)(u >> 16);
            alr[j] = f2bf(av[j] - __uint_as_float(u & 0xffff0000u));
        }
        char* AsH = lds; char* AsL = lds + 8192;
        char* BsH = lds + 16384; char* BsL = lds + 24576;
        *(uint4*)(AsH + wo0) = *(const uint4*)&ah[0];
        *(uint4*)(AsH + wo1) = *(const uint4*)&ah[8];
        *(uint4*)(AsL + wo0) = *(const uint4*)&alr[0];
        *(uint4*)(AsL + wo1) = *(const uint4*)&alr[8];
        *(uint4*)(BsH + wo0) = rbh0; *(uint4*)(BsH + wo1) = rbh1;
        *(uint4*)(BsL + wo0) = rbl0; *(uint4*)(BsL + wo1) = rbl1;
    }
    __syncthreads();
    for (int i = 0; i < niter; ++i) {
        bool more = (i + 1 < niter);
        if (more) {
            int gk = kbeg + (i + 1) * 32 + akp;
            #pragma unroll
            for (int j = 0; j < 16; j += 4) {
                float4 v = (arok && gk + j < NGENE) ? *(const float4*)(arowp + gk + j)
                                                    : make_float4(0.f, 0.f, 0.f, 0.f);
                av[j] = v.x; av[j + 1] = v.y; av[j + 2] = v.z; av[j + 3] = v.w;
            }
            rbh0 = *(const uint4*)(bhp + gk); rbh1 = *(const uint4*)(bhp + gk + 8);
            rbl0 = *(const uint4*)(blp + gk); rbl1 = *(const uint4*)(blp + gk + 8);
        }
        {
            char* base = lds + (i & 1) * 32768;
            char* AsH = base; char* AsL = base + 8192;
            char* BsH = base + 16384; char* BsL = base + 24576;
            bf16x8 afh[4], afl[4], bfh[4], bfl[4];
            #pragma unroll
            for (int m = 0; m < 4; ++m) {
                int Bb = (wr * 64 + m * 16 + r16) * 64 + soA;
                afh[m] = *(const bf16x8*)(AsH + Bb);
                afl[m] = *(const bf16x8*)(AsL + Bb);
            }
            #pragma unroll
            for (int n = 0; n < 4; ++n) {
                int Bb = (wc * 64 + n * 16 + r16) * 64 + soA;
                bfh[n] = *(const bf16x8*)(BsH + Bb);
                bfl[n] = *(const bf16x8*)(BsL + Bb);
            }
            #pragma unroll
            for (int m = 0; m < 4; ++m)
                #pragma unroll
                for (int n = 0; n < 4; ++n) {
                    acc[m][n] = __builtin_amdgcn_mfma_f32_16x16x32_bf16(afh[m], bfh[n], acc[m][n], 0, 0, 0);
                    acc[m][n] = __builtin_amdgcn_mfma_f32_16x16x32_bf16(afh[m], bfl[n], acc[m][n], 0, 0, 0);
                    acc[m][n] = __builtin_amdgcn_mfma_f32_16x16x32_bf16(afl[m], bfh[n], acc[m][n], 0, 0, 0);
                }
        }
        if (more) {
            unsigned short ah[16], alr[16];
            #pragma unroll
            for (int j = 0; j < 16; ++j) {
                unsigned u = __float_as_uint(av[j]);
                ah[j] = (unsigned short)(u >> 16);
                alr[j] = f2bf(av[j] - __uint_as_float(u & 0xffff0000u));
            }
            char* base = lds + ((i + 1) & 1) * 32768;
            char* AsH = base; char* AsL = base + 8192;
            char* BsH = base + 16384; char* BsL = base + 24576;
            *(uint4*)(AsH + wo0) = *(const uint4*)&ah[0];
            *(uint4*)(AsH + wo1) = *(const uint4*)&ah[8];
            *(uint4*)(AsL + wo0) = *(const uint4*)&alr[0];
            *(uint4*)(AsL + wo1) = *(const uint4*)&alr[8];
            *(uint4*)(BsH + wo0) = rbh0; *(uint4*)(BsH + wo1) = rbh1;
            *(uint4*)(BsL + wo0) = rbl0; *(uint4*)(BsL + wo1) = rbl1;
        }
        __syncthreads();
    }
    #pragma unroll
    for (int m = 0; m < 4; ++m) {
        #pragma unroll
        for (int n = 0; n < 4; ++n) {
            #pragma unroll
            for (int r = 0; r < 4; ++r) {
                int rowg = row0 + wr * 64 + m * 16 + g * 4 + r;
                int colg = col0 + wc * 64 + n * 16 + r16;
                if (rowg < NGENE)
                    part[((long)z * NGENE + rowg) * H1 + colg] = acc[m][n][r];
            }
        }
    }
}

// ---------------- split-K reduce ----------------
__global__ __launch_bounds__(256) void reduce_splitk_kernel(const float* __restrict__ part,
                                                            const float* __restrict__ bias,
                                                            unsigned short* __restrict__ xh,
                                                            unsigned short* __restrict__ xl)
{
    const long NEL = (long)NGENE * H1;
    long stride = (long)gridDim.x * blockDim.x;
    for (long q = (long)blockIdx.x * blockDim.x + threadIdx.x; q * 4 < NEL; q += stride) {
        long e = q * 4;
        float4 sv = *(const float4*)(part + e);
        #pragma unroll
        for (int z = 1; z < ZSPLIT; ++z) {
            float4 t = *(const float4*)(part + (long)z * NEL + e);
            sv.x += t.x; sv.y += t.y; sv.z += t.z; sv.w += t.w;
        }
        int col = (int)(e & (H1 - 1));
        float4 b = *(const float4*)(bias + col);
        float v[4] = {sv.x + b.x, sv.y + b.y, sv.z + b.z, sv.w + b.w};
        unsigned short oh[4], ol[4];
        #pragma unroll
        for (int i = 0; i < 4; ++i) {
            oh[i] = f2bf(v[i]);
            ol[i] = f2bf(v[i] - bf2f(oh[i]));
        }
        long o = (long)(NDRUG + NCELL) * H1 + e;
        *(uint2*)(xh + o) = *(const uint2*)oh;
        *(uint2*)(xl + o) = *(const uint2*)ol;
    }
}

// ---------------- init kernels ----------------
__global__ void init1_kernel(float* m, int* deg, float* colstats, float* scal)
{
    int i = blockIdx.x * 256 + threadIdx.x;
    if (i < NNODE * 4) m[i] = -3.402823466e38f;
    if (i < NNODE) deg[i] = 0;
    if (i < 1024) colstats[i] = 0.f;
    if (i < 8) scal[i] = 0.f;
}

__global__ void init2_kernel(float* m, float* colstats)
{
    int i = blockIdx.x * 256 + threadIdx.x;
    if (i < NNODE * 4) m[i] = -3.402823466e38f;
    if (i < 1024) colstats[i] = 0.f;
}

// ---------------- fused: sum(edge_attr)->scal[0] + ce ----------------
__global__ __launch_bounds__(512) void small_pre_kernel(const float* __restrict__ eattr, float* scal,
                                                        const float* We1, const float* ae1,
                                                        const float* We2, const float* ae2, float* ce)
{
    if (blockIdx.x < 64) {
        float s = 0.f;
        for (int i = blockIdx.x * 512 + threadIdx.x; i < E0; i += 64 * 512)
            s += eattr[i];
        for (int off = 32; off; off >>= 1) s += __shfl_down(s, off);
        if ((threadIdx.x & 63) == 0) atomicAdd(&scal[0], s);
    } else {
        __shared__ float sm[512];
        int t = threadIdx.x;
        sm[t] = We1[t] * ae1[t];
        __syncthreads();
        if (t < 4) { float s = 0.f; for (int c = 0; c < 128; ++c) s += sm[t * 128 + c]; ce[t] = s; }
        __syncthreads();
        sm[t] = We2[t] * ae2[t];
        __syncthreads();
        if (t < 4) { float s = 0.f; for (int c = 0; c < 128; ++c) s += sm[t * 128 + c]; ce[4 + t] = s; }
    }
}

// ---------------- degree histogram ----------------
__global__ void deg_kernel(const int* __restrict__ ei, int* __restrict__ deg)
{
    int e = blockIdx.x * blockDim.x + threadIdx.x;
    if (e >= ET) return;
    int d = (e < E0) ? ei[E0 + e] : (e - E0);
    atomicAdd(&deg[d], 1);
}

// ---------------- exclusive scan ----------------
__global__ __launch_bounds__(1024) void scan_kernel(const int* __restrict__ deg,
                                                    int* __restrict__ row_start,
                                                    int* __restrict__ cursor)
{
    __shared__ int sm[1024];
    int t = threadIdx.x;
    int base = t * 8;
    int loc[8];
    int sum = 0;
    #pragma unroll
    for (int j = 0; j < 8; ++j) {
        int v = (base + j < NNODE) ? deg[base + j] : 0;
        loc[j] = sum; sum += v;
    }
    sm[t] = sum;
    __syncthreads();
    for (int off = 1; off < 1024; off <<= 1) {
        int v = (t >= off) ? sm[t - off] : 0;
        __syncthreads();
        sm[t] += v;
        __syncthreads();
    }
    int excl = sm[t] - sum;
    #pragma unroll
    for (int j = 0; j < 8; ++j) {
        int idx = base + j;
        if (idx < NNODE) { int v = excl + loc[j]; row_start[idx] = v; cursor[idx] = v; }
    }
    if (t == 1023) row_start[NNODE] = sm[1023];
}

// ---------------- scatter edge structure into CSR ----------------
__global__ void scatter_csr_kernel(const int* __restrict__ ei, int* __restrict__ cursor,
                                   int* __restrict__ csr_src, int* __restrict__ pos_of_e)
{
    int e = blockIdx.x * blockDim.x + threadIdx.x;
    if (e >= ET) return;
    int s, d;
    if (e < E0) { s = ei[e]; d = ei[E0 + e]; }
    else        { s = d = e - E0; }
    int pos = atomicAdd(&cursor[d], 1);
    csr_src[pos] = s;
    pos_of_e[e] = pos;
}

// ---------------- per-node attention coefficients (4 nodes per block) ----------------
__global__ __launch_bounds__(256) void attn_coef_kernel(const float* __restrict__ xw,
                                                        const float* __restrict__ as,
                                                        const float* __restrict__ ad,
                                                        float* __restrict__ a_src,
                                                        float* __restrict__ a_dst)
{
    int n = blockIdx.x * 4 + (threadIdx.x >> 6);
    int l = threadIdx.x & 63;
    #pragma unroll
    for (int h = 0; h < 4; ++h) {
        float x1 = xw[(long)n * HD + h * 128 + l];
        float x2 = xw[(long)n * HD + h * 128 + 64 + l];
        float s = x1 * as[h * 128 + l] + x2 * as[h * 128 + 64 + l];
        float d = x1 * ad[h * 128 + l] + x2 * ad[h * 128 + 64 + l];
        for (int off = 32; off; off >>= 1) { s += __shfl_down(s, off); d += __shfl_down(d, off); }
        if (l == 0) { a_src[n * 4 + h] = s; a_dst[n * 4 + h] = d; }
    }
}

// ---------------- atomic float max ----------------
__device__ inline void atomicMaxF(float* addr, float v)
{
    if (v >= 0.f) atomicMax((int*)addr, __float_as_int(v));
    else          atomicMin((unsigned int*)addr, __float_as_uint(v));
}

// ---------------- per-edge alpha (scatter to CSR order) + segment max ----------------
__global__ void alpha_max_kernel(const int* __restrict__ ei, const float* __restrict__ eattr,
                                 const float* __restrict__ scal,
                                 const float* __restrict__ a_src, const float* __restrict__ a_dst,
                                 const float* __restrict__ ce,
                                 float* __restrict__ csr_alpha,
                                 const int* __restrict__ pos_of_e,
                                 float* __restrict__ m)
{
    int e = blockIdx.x * blockDim.x + threadIdx.x;
    if (e >= ET) return;
    int s, d; float a;
    if (e < E0) { s = ei[e]; d = ei[E0 + e]; a = eattr[e]; }
    else        { s = d = e - E0; a = scal[0] * (1.0f / E0); }
    float4 av;
    float* avp = (float*)&av;
    #pragma unroll
    for (int h = 0; h < 4; ++h) {
        float v = a_src[s * 4 + h] + a_dst[d * 4 + h] + a * ce[h];
        v = v > 0.f ? v : 0.2f * v;
        avp[h] = v;
        atomicMaxF(&m[d * 4 + h], v);
    }
    *(float4*)(csr_alpha + (long)pos_of_e[e] * 4) = av;
}

// ---------------- aggregation ----------------
__global__ __launch_bounds__(256) void aggregate_kernel(const unsigned short* __restrict__ xwb,
                                                        const float* __restrict__ csr_alpha,
                                                        const float* __restrict__ m,
                                                        const int* __restrict__ rs,
                                                        const int* __restrict__ csr_src,
                                                        const float* __restrict__ bias,
                                                        float* __restrict__ out)
{
    int n = blockIdx.x;
    int h = threadIdx.x >> 6;
    int l = threadIdx.x & 63;
    float mnh = m[n * 4 + h];
    int i0 = rs[n], i1 = rs[n + 1];
    float den = 0.f;
    for (int i = i0 + l; i < i1; i += 64)
        den += expf(csr_alpha[(long)i * 4 + h] - mnh);
    for (int off = 32; off; off >>= 1) den += __shfl_down(den, off);
    den = __shfl(den, 0);
    float rden = 1.0f / (den + 1e-16f);
    float acc0 = 0.f, acc1 = 0.f;
    int i = i0;
    for (; i + 7 < i1; i += 8) {
        int      sv[8];
        float    av[8];
        unsigned xv[8];
        #pragma unroll
        for (int j = 0; j < 8; ++j) {
            sv[j] = csr_src[i + j];
            av[j] = csr_alpha[(long)(i + j) * 4 + h];
        }
        #pragma unroll
        for (int j = 0; j < 8; ++j)
            xv[j] = *(const unsigned*)(xwb + (long)sv[j] * HD + h * 128 + 2 * l);
        #pragma unroll
        for (int j = 0; j < 8; ++j) {
            float w = expf(av[j] - mnh);
            acc0 += w * bf2f((unsigned short)(xv[j] & 0xffffu));
            acc1 += w * bf2f((unsigned short)(xv[j] >> 16));
        }
    }
    for (; i < i1; ++i) {
        int s = csr_src[i];
        float w = expf(csr_alpha[(long)i * 4 + h] - mnh);
        unsigned x = *(const unsigned*)(xwb + (long)s * HD + h * 128 + 2 * l);
        acc0 += w * bf2f((unsigned short)(x & 0xffffu));
        acc1 += w * bf2f((unsigned short)(x >> 16));
    }
    float2 o;
    o.x = acc0 * rden + bias[h * 128 + 2 * l];
    o.y = acc1 * rden + bias[h * 128 + 2 * l + 1];
    *(float2*)(out + (long)n * HD + h * 128 + 2 * l) = o;
}

// ---------------- graph norm: fused column sum + sum-of-squares (250 blocks x 32 rows) --------
__global__ __launch_bounds__(256) void colstats_kernel(const float* __restrict__ x,
                                                       float* __restrict__ colsum,
                                                       float* __restrict__ colsumsq)
{
    int t = threadIdx.x, b = blockIdx.x;
    float s0 = 0.f, s1 = 0.f, q0 = 0.f, q1 = 0.f;
    int r0 = b * 32, r1e = r0 + 32;
    for (int r = r0; r < r1e; ++r) {
        float v0 = x[(long)r * HD + t];
        float v1 = x[(long)r * HD + t + 256];
        s0 += v0; q0 += v0 * v0;
        s1 += v1; q1 += v1 * v1;
    }
    atomicAdd(&colsum[t], s0);
    atomicAdd(&colsum[t + 256], s1);
    atomicAdd(&colsumsq[t], q0);
    atomicAdd(&colsumsq[t + 256], q1);
}

// norm (+ReLU) in place; writes hi/lo bf16 copies
__global__ void norm_kernel(float* __restrict__ x,
                            unsigned short* __restrict__ xbh, unsigned short* __restrict__ xbl,
                            const float* __restrict__ colsum,
                            const float* __restrict__ colsumsq,
                            const float* __restrict__ g, const float* __restrict__ be,
                            const float* __restrict__ ms)
{
    int stride = gridDim.x * blockDim.x;
    for (int idx = blockIdx.x * blockDim.x + threadIdx.x; idx < NNODE * HD; idx += stride) {
        int j = idx & 511;
        float mu  = colsum[j] * (1.0f / NNODE);
        float ex2 = colsumsq[j] * (1.0f / NNODE);
        float msj = ms[j];
        float var = ex2 - msj * (2.0f - msj) * mu * mu;
        float v = x[idx] - msj * mu;
        float y = g[j] * v / sqrtf(var + 1e-5f) + be[j];
        y = y > 0.f ? y : 0.f;
        x[idx] = y;
        unsigned short h = f2bf(y);
        xbh[idx] = h;
        xbl[idx] = f2bf(y - bf2f(h));
    }
}

// ---------------- prediction head ----------------
__global__ __launch_bounds__(256) void head_kernel(const float* __restrict__ x2,
                                                   const int* __restrict__ idd,
                                                   const int* __restrict__ idc,
                                                   const float* __restrict__ Wout,
                                                   const float* __restrict__ bout,
                                                   float* __restrict__ out0)
{
    int w = threadIdx.x >> 6, l = threadIdx.x & 63;
    int b = blockIdx.x * 4 + w;
    if (b >= BSZ) return;
    int rd = idd[b], rc = idc[b];
    float s = 0.f;
    #pragma unroll
    for (int k = l; k < HD; k += 64)
        s += x2[(long)rd * HD + k] * Wout[k] + x2[(long)rc * HD + k] * Wout[HD + k];
    for (int off = 32; off; off >>= 1) s += __shfl_down(s, off);
    if (l == 0) out0[b] = s + bout[0];
}

// ---------------- all_att: zero + scatter scalar ----------------
__global__ void zero_f4_kernel(float4* __restrict__ p, long n4)
{
    long stride = (long)gridDim.x * blockDim.x;
    for (long i = (long)blockIdx.x * blockDim.x + threadIdx.x; i < n4; i += stride)
        p[i] = make_float4(0.f, 0.f, 0.f, 0.f);
}

__global__ void scatter_att_kernel(const int* __restrict__ ei, float* __restrict__ attm)
{
    int e = blockIdx.x * blockDim.x + threadIdx.x;
    if (e >= ET) return;
    int s, d;
    if (e < E0) { s = ei[e]; d = ei[E0 + e]; }
    else        { s = d = e - E0; }
    const float val = 2.0f * (float)NNODE / (float)ET;
    attm[(long)s * NNODE + d] = val;
}

// ---------------- launch ----------------
extern "C" void kernel_launch(void* const* d_in, const int* in_sizes, int n_in,
                              void* d_out, int out_size, void* d_ws, size_t ws_size,
                              hipStream_t stream)
{
    const float* drug   = (const float*)d_in[0];
    const float* cell   = (const float*)d_in[1];
    const float* gene   = (const float*)d_in[2];
    const float* eattr  = (const float*)d_in[3];
    const int*   ei     = (const int*)d_in[4];
    const int*   idd    = (const int*)d_in[5];
    const int*   idc    = (const int*)d_in[6];
    const float* Wdrug  = (const float*)d_in[7];
    const float* bdrug  = (const float*)d_in[8];
    const float* Wcell  = (const float*)d_in[9];
    const float* bcell  = (const float*)d_in[10];
    const float* Wgene  = (const float*)d_in[11];
    const float* bgene  = (const float*)d_in[12];
    const float* W1     = (const float*)d_in[13];
    const float* b1     = (const float*)d_in[14];
    const float* as1    = (const float*)d_in[15];
    const float* ad1    = (const float*)d_in[16];
    const float* We1    = (const float*)d_in[17];
    const float* ae1    = (const float*)d_in[18];
    const float* bias1  = (const float*)d_in[19];
    const float* g1     = (const float*)d_in[20];
    const float* be1    = (const float*)d_in[21];
    const float* ms1    = (const float*)d_in[22];
    const float* W2     = (const float*)d_in[23];
    const float* b2     = (const float*)d_in[24];
    const float* as2    = (const float*)d_in[25];
    const float* ad2    = (const float*)d_in[26];
    const float* We2    = (const float*)d_in[27];
    const float* ae2    = (const float*)d_in[28];
    const float* bias2  = (const float*)d_in[29];
    const float* g2     = (const float*)d_in[30];
    const float* be2    = (const float*)d_in[31];
    const float* ms2    = (const float*)d_in[32];
    const float* Wout   = (const float*)d_in[33];
    const float* bout   = (const float*)d_in[34];

    float* out0 = (float*)d_out;                 // [10000]
    float* attm = (float*)d_out + BSZ;           // [8000*8000]

    // ---- workspace layout ----
    float* ws     = (float*)d_ws;
    float* xw     = ws;                          // 8000*512
    float* outb   = xw + (long)NNODE * HD;       // 8000*512
    float* csr_al = outb + (long)NNODE * HD;     // 168000*4
    float* a_src  = csr_al + (long)ET * 4;       // 32000
    float* a_dst  = a_src + NNODE * 4;           // 32000
    float* mbuf   = a_dst + NNODE * 4;           // 32000
    float* colsum = mbuf + NNODE * 4;            // 512
    float* colsq  = colsum + 512;                // 512
    float* ce     = colsq + 512;                 // 8
    float* scal   = ce + 8;                      // 8
    int* deg      = (int*)(scal + 8);            // 8000
    int* rs       = deg + NNODE;                 // 8004
    int* cursor   = rs + NNODE + 4;              // 8000
    int* csr_src  = cursor + NNODE;              // 168000
    int* pos_of_e = csr_src + ET;                // 168000
    unsigned short* p = (unsigned short*)(pos_of_e + ET);
    unsigned short* xwb    = p; p += (long)NNODE * HD;
    unsigned short* drug_h = p; p += (long)1024 * 1024;
    unsigned short* drug_l = p; p += (long)1024 * 1024;
    unsigned short* cell_h = p; p += (long)1024 * 1024;
    unsigned short* cell_l = p; p += (long)1024 * 1024;
    unsigned short* x0_h   = p; p += (long)NNODE * H1;
    unsigned short* x0_l   = p; p += (long)NNODE * H1;
    unsigned short* xb_h   = p; p += (long)NNODE * HD;
    unsigned short* xb_l   = p; p += (long)NNODE * HD;
    unsigned short* Wd_h   = p; p += 256 * 1024;
    unsigned short* Wd_l   = p; p += 256 * 1024;
    unsigned short* Wc_h   = p; p += 256 * 1024;
    unsigned short* Wc_l   = p; p += 256 * 1024;
    unsigned short* Wg_h   = p; p += 256 * GKP;
    unsigned short* Wg_l   = p; p += 256 * GKP;
    unsigned short* W1_h   = p; p += 512 * 256;
    unsigned short* W1_l   = p; p += 512 * 256;
    unsigned short* W2_h   = p; p += 512 * 512;
    unsigned short* W2_l   = p; p += 512 * 512;
    float* partsk = (float*)((((unsigned long long)p) + 15) & ~15ULL);

    dim3 blk256(256);
    int gE = (ET + 255) / 256;

    // init + CSR build + small precomputes
    init1_kernel<<<125, blk256, 0, stream>>>(mbuf, deg, colsum, scal);
    deg_kernel<<<gE, blk256, 0, stream>>>(ei, deg);
    scan_kernel<<<1, 1024, 0, stream>>>(deg, rs, cursor);
    scatter_csr_kernel<<<gE, blk256, 0, stream>>>(ei, cursor, csr_src, pos_of_e);
    small_pre_kernel<<<65, 512, 0, stream>>>(eattr, scal, We1, ae1, We2, ae2, ce);

    // ---- conversions ----
    cvt_pad2_dc_kernel<<<1024, blk256, 0, stream>>>(drug, drug_h, drug_l, cell, cell_h, cell_l);
    {
        TC5 d;
        d.W[0] = Wdrug; d.Wh[0] = Wd_h; d.Wl[0] = Wd_l; d.K[0] = NDRUG; d.N[0] = H1; d.Kp[0] = 1024; d.gx[0] = 32;
        d.W[1] = Wcell; d.Wh[1] = Wc_h; d.Wl[1] = Wc_l; d.K[1] = NCELL; d.N[1] = H1; d.Kp[1] = 1024; d.gx[1] = 32;
        d.W[2] = Wgene; d.Wh[2] = Wg_h; d.Wl[2] = Wg_l; d.K[2] = NGENE; d.N[2] = H1; d.Kp[2] = GKP;  d.gx[2] = 188;
        d.W[3] = W1;    d.Wh[3] = W1_h; d.Wl[3] = W1_l; d.K[3] = H1;    d.N[3] = HD; d.Kp[3] = H1;   d.gx[3] = 8;
        d.W[4] = W2;    d.Wh[4] = W2_h; d.Wl[4] = W2_l; d.K[4] = HD;    d.N[4] = HD; d.Kp[4] = HD;   d.gx[4] = 16;
        d.start[0] = 0;    d.start[1] = 256;  d.start[2] = 512;
        d.start[3] = 2016; d.start[4] = 2144; d.start[5] = 2400;
        transpose_cvt2_batch<<<2400, blk256, 0, stream>>>(d);
    }

    // ---- input projections -> x0 (hi/lo bf16) ----
    gemm_mfma2<1><<<dim3(H1 / 64, 16), blk256, 0, stream>>>(drug_h, drug_l, Wd_h, Wd_l, bdrug,
        nullptr, x0_h, x0_l, nullptr, NDRUG, 1024, H1);
    gemm_mfma2<1><<<dim3(H1 / 64, 16), blk256, 0, stream>>>(cell_h, cell_l, Wc_h, Wc_l, bcell,
        nullptr, x0_h + (long)NDRUG * H1, x0_l + (long)NDRUG * H1, nullptr, NCELL, 1024, H1);
    gemm_gene_f32<<<752, blk256, 0, stream>>>(gene, Wg_h, Wg_l, partsk);
    reduce_splitk_kernel<<<1500, blk256, 0, stream>>>(partsk, bgene, x0_h, x0_l);

    // ---- layer 1 ----
    gemm_mfma2<0><<<dim3(HD / 64, NNODE / 64), blk256, 0, stream>>>(x0_h, x0_l, W1_h, W1_l, b1,
        xw, nullptr, nullptr, xwb, NNODE, H1, HD);
    attn_coef_kernel<<<NNODE / 4, blk256, 0, stream>>>(xw, as1, ad1, a_src, a_dst);
    alpha_max_kernel<<<gE, blk256, 0, stream>>>(ei, eattr, scal, a_src, a_dst, ce,
        csr_al, pos_of_e, mbuf);
    aggregate_kernel<<<NNODE, blk256, 0, stream>>>(xwb, csr_al, mbuf, rs, csr_src, bias1, outb);
    colstats_kernel<<<250, blk256, 0, stream>>>(outb, colsum, colsq);
    norm_kernel<<<2048, blk256, 0, stream>>>(outb, xb_h, xb_l, colsum, colsq, g1, be1, ms1);

    // ---- layer 2 ----
    gemm_mfma2<0><<<dim3(HD / 64, NNODE / 64), blk256, 0, stream>>>(xb_h, xb_l, W2_h, W2_l, b2,
        xw, nullptr, nullptr, xwb, NNODE, HD, HD);
    attn_coef_kernel<<<NNODE / 4, blk256, 0, stream>>>(xw, as2, ad2, a_src, a_dst);
    init2_kernel<<<125, blk256, 0, stream>>>(mbuf, colsum);
    alpha_max_kernel<<<gE, blk256, 0, stream>>>(ei, eattr, scal, a_src, a_dst, ce + 4,
        csr_al, pos_of_e, mbuf);
    aggregate_kernel<<<NNODE, blk256, 0, stream>>>(xwb, csr_al, mbuf, rs, csr_src, bias2, outb);
    colstats_kernel<<<250, blk256, 0, stream>>>(outb, colsum, colsq);
    norm_kernel<<<2048, blk256, 0, stream>>>(outb, xb_h, xb_l, colsum, colsq, g2, be2, ms2);

    // ---- head + attention matrix ----
    head_kernel<<<(BSZ + 3) / 4, blk256, 0, stream>>>(outb, idd, idc, Wout, bout, out0);
    zero_f4_kernel<<<2048, blk256, 0, stream>>>((float4*)attm, (long)NNODE * NNODE / 4);
    scatter_att_kernel<<<gE, blk256, 0, stream>>>(ei, attm);
}

// Round 18
// 525.988 us; speedup vs baseline: 1.1810x; 1.0095x over previous
//
#include <hip/hip_runtime.h>
#include <math.h>

// ---------------- problem constants ----------------
#define NDRUG 1000
#define NCELL 1000
#define NGENE 6000
#define NNODE 8000
#define H1 256
#define HD  512
#define E0  160000
#define ET  168000
#define BSZ 10000
#define GKP 6016
#define ZSPLIT 8
#define ZCH 768

typedef __attribute__((ext_vector_type(8))) short bf16x8;
typedef __attribute__((ext_vector_type(4))) float f32x4;

__device__ inline unsigned short f2bf(float f)
{
    unsigned u = __float_as_uint(f);
    u += 0x7fffu + ((u >> 16) & 1u);   // RNE
    return (unsigned short)(u >> 16);
}
__device__ inline float bf2f(unsigned short h)
{
    return __uint_as_float(((unsigned)h) << 16);
}

// ---------------- drug+cell f32 -> (hi,lo) bf16 with padding, one launch ----------------
__global__ void cvt_pad2_dc_kernel(const float* __restrict__ drug, unsigned short* dh, unsigned short* dl,
                                   const float* __restrict__ cell, unsigned short* ch, unsigned short* cl)
{
    const float* in;
    unsigned short *hi, *lo;
    long u0;
    if (blockIdx.x < 512) { in = drug; hi = dh; lo = dl; u0 = (long)blockIdx.x * 256 + threadIdx.x; }
    else                  { in = cell; hi = ch; lo = cl; u0 = (long)(blockIdx.x - 512) * 256 + threadIdx.x; }
    const long total = (long)1024 * 1024 / 8;
    for (long u = u0; u < total; u += 512 * 256) {
        long row = u / 128; int kc = (int)(u % 128);
        unsigned short oh[8], ol[8];
        if (row < 1000 && kc * 8 < 1000) {
            const float* p = in + row * 1000 + kc * 8;
            float4 a = *(const float4*)p, b = *(const float4*)(p + 4);
            float v[8] = {a.x, a.y, a.z, a.w, b.x, b.y, b.z, b.w};
            #pragma unroll
            for (int i = 0; i < 8; ++i) {
                unsigned short h = f2bf(v[i]);
                oh[i] = h;
                ol[i] = f2bf(v[i] - bf2f(h));
            }
        } else {
            #pragma unroll
            for (int i = 0; i < 8; ++i) { oh[i] = 0; ol[i] = 0; }
        }
        *(uint4*)(hi + u * 8) = *(const uint4*)oh;
        *(uint4*)(lo + u * 8) = *(const uint4*)ol;
    }
}

// ---------------- batched W[K][N] -> Wt_{hi,lo}[N][Kp], 5 weights in one launch ----------------
struct TC5 {
    const float* W[5];
    unsigned short* Wh[5];
    unsigned short* Wl[5];
    int K[5]; int N[5]; int Kp[5]; int gx[5];
    int start[6];
};

__global__ __launch_bounds__(256) void transpose_cvt2_batch(TC5 d)
{
    int bid = blockIdx.x;
    int idx = 0;
    #pragma unroll
    for (int i = 1; i < 5; ++i) if (bid >= d.start[i]) idx = i;
    int local = bid - d.start[idx];
    int gx = d.gx[idx];
    int K = d.K[idx], N = d.N[idx], Kp = d.Kp[idx];
    const float* W = d.W[idx];
    unsigned short* Wh = d.Wh[idx];
    unsigned short* Wl = d.Wl[idx];
    __shared__ float t[32][33];
    int kb = (local % gx) * 32, nb = (local / gx) * 32;
    int tx = threadIdx.x & 31, ty = threadIdx.x >> 5;
    #pragma unroll
    for (int i = 0; i < 32; i += 8) {
        int k = kb + ty + i;
        t[ty + i][tx] = (k < K) ? W[(long)k * N + nb + tx] : 0.f;
    }
    __syncthreads();
    #pragma unroll
    for (int i = 0; i < 32; i += 8) {
        int n = nb + ty + i;
        float v = t[tx][ty + i];
        unsigned short h = f2bf(v);
        Wh[(long)n * Kp + kb + tx] = h;
        Wl[(long)n * Kp + kb + tx] = f2bf(v - bf2f(h));
    }
}

// ---------------- split-bf16 MFMA GEMM, 64x64 tile ----------------
template<int OUTBF>
__global__ __launch_bounds__(256) void gemm_mfma2(const unsigned short* __restrict__ Ah,
                                                  const unsigned short* __restrict__ Al,
                                                  const unsigned short* __restrict__ Bh,
                                                  const unsigned short* __restrict__ Bl,
                                                  const float* __restrict__ bias,
                                                  float* __restrict__ Cf,
                                                  unsigned short* __restrict__ Cbh,
                                                  unsigned short* __restrict__ Cbl,
                                                  unsigned short* __restrict__ Cx,
                                                  int M, int Kp, int N)
{
    __shared__ unsigned short AsH[64 * 64];
    __shared__ unsigned short AsL[64 * 64];
    __shared__ unsigned short BsH[64 * 64];
    __shared__ unsigned short BsL[64 * 64];
    char* AsH8 = (char*)AsH; char* AsL8 = (char*)AsL;
    char* BsH8 = (char*)BsH; char* BsL8 = (char*)BsL;
    int tid = threadIdx.x;
    int w = tid >> 6, l = tid & 63;
    int wr = w >> 1, wc = w & 1;
    int g = l >> 4, r16 = l & 15;
    int row0 = blockIdx.y * 64, col0 = blockIdx.x * 64;
    int srow = tid >> 3, skc = tid & 7;
    int B0 = srow * 128 + skc * 16;       int P0 = B0 ^ ((srow & 7) << 4);
    int r1 = srow + 32;                   int B1 = r1 * 128 + skc * 16;
    int P1 = B1 ^ ((r1 & 7) << 4);
    f32x4 acc[2][2] = {};
    for (int k0 = 0; k0 < Kp; k0 += 64) {
        long a0 = (long)(row0 + srow) * Kp + k0 + skc * 8;
        long a1 = (long)(row0 + srow + 32) * Kp + k0 + skc * 8;
        long b0 = (long)(col0 + srow) * Kp + k0 + skc * 8;
        long b1 = (long)(col0 + srow + 32) * Kp + k0 + skc * 8;
        uint4 ah0 = *(const uint4*)(Ah + a0); uint4 ah1 = *(const uint4*)(Ah + a1);
        uint4 al0 = *(const uint4*)(Al + a0); uint4 al1 = *(const uint4*)(Al + a1);
        uint4 bh0 = *(const uint4*)(Bh + b0); uint4 bh1 = *(const uint4*)(Bh + b1);
        uint4 bl0 = *(const uint4*)(Bl + b0); uint4 bl1 = *(const uint4*)(Bl + b1);
        __syncthreads();
        *(uint4*)(AsH8 + P0) = ah0; *(uint4*)(AsH8 + P1) = ah1;
        *(uint4*)(AsL8 + P0) = al0; *(uint4*)(AsL8 + P1) = al1;
        *(uint4*)(BsH8 + P0) = bh0; *(uint4*)(BsH8 + P1) = bh1;
        *(uint4*)(BsL8 + P0) = bl0; *(uint4*)(BsL8 + P1) = bl1;
        __syncthreads();
        #pragma unroll
        for (int kk = 0; kk < 2; ++kk) {
            bf16x8 afh[2], afl[2], bfh[2], bfl[2];
            #pragma unroll
            for (int m = 0; m < 2; ++m) {
                int row = wr * 32 + m * 16 + r16;
                int Bb = (row * 128 + kk * 64 + g * 16) ^ ((row & 7) << 4);
                afh[m] = *(const bf16x8*)(AsH8 + Bb);
                afl[m] = *(const bf16x8*)(AsL8 + Bb);
            }
            #pragma unroll
            for (int n = 0; n < 2; ++n) {
                int row = wc * 32 + n * 16 + r16;
                int Bb = (row * 128 + kk * 64 + g * 16) ^ ((row & 7) << 4);
                bfh[n] = *(const bf16x8*)(BsH8 + Bb);
                bfl[n] = *(const bf16x8*)(BsL8 + Bb);
            }
            #pragma unroll
            for (int m = 0; m < 2; ++m)
                #pragma unroll
                for (int n = 0; n < 2; ++n) {
                    acc[m][n] = __builtin_amdgcn_mfma_f32_16x16x32_bf16(afh[m], bfh[n], acc[m][n], 0, 0, 0);
                    acc[m][n] = __builtin_amdgcn_mfma_f32_16x16x32_bf16(afh[m], bfl[n], acc[m][n], 0, 0, 0);
                    acc[m][n] = __builtin_amdgcn_mfma_f32_16x16x32_bf16(afl[m], bfh[n], acc[m][n], 0, 0, 0);
                }
        }
    }
    #pragma unroll
    for (int m = 0; m < 2; ++m) {
        #pragma unroll
        for (int n = 0; n < 2; ++n) {
            #pragma unroll
            for (int r = 0; r < 4; ++r) {
                int rowg = row0 + wr * 32 + m * 16 + g * 4 + r;
                int colg = col0 + wc * 32 + n * 16 + r16;
                if (rowg < M) {
                    float v = acc[m][n][r] + bias[colg];
                    if (OUTBF) {
                        unsigned short h = f2bf(v);
                        Cbh[(long)rowg * N + colg] = h;
                        Cbl[(long)rowg * N + colg] = f2bf(v - bf2f(h));
                    } else {
                        Cf[(long)rowg * N + colg] = v;
                        Cx[(long)rowg * N + colg] = f2bf(v);
                    }
                }
            }
        }
    }
}

// ---------------- gene GEMM: f32 A, ping-pong double buffer, ONE barrier/iter ----------------
__global__ __launch_bounds__(256) void gemm_gene_f32(const float* __restrict__ A,
                                                     const unsigned short* __restrict__ Bh,
                                                     const unsigned short* __restrict__ Bl,
                                                     float* __restrict__ part)
{
    __shared__ char lds[65536];
    int tid = threadIdx.x;
    int w = tid >> 6, l = tid & 63;
    int wr = w >> 1, wc = w & 1;
    int g = l >> 4, r16 = l & 15;
    int pid = blockIdx.x;
    int L = (pid & 7) * 94 + (pid >> 3);
    int xb = L & 1;
    int yb = (L >> 1) % 47;
    int z  = L / 94;
    int row0 = yb * 128, col0 = xb * 128;
    int kbeg = z * ZCH;
    int kend = kbeg + ZCH; if (kend > GKP) kend = GKP;
    int niter = (kend - kbeg) >> 5;
    int arow = tid >> 1, akp = (tid & 1) * 16;
    int t_ar = (arow + (arow >> 2)) & 3;
    int s0 = akp >> 3;
    int wo0 = arow * 64 + ((s0 ^ t_ar) << 4);
    int wo1 = arow * 64 + (((s0 + 1) ^ t_ar) << 4);
    int tA = (r16 + (r16 >> 2)) & 3;
    int soA = (g ^ tA) << 4;
    int gr = row0 + arow;
    const float* arowp = A + (long)gr * NGENE;
    const unsigned short* bhp = Bh + (long)(col0 + arow) * GKP;
    const unsigned short* blp = Bl + (long)(col0 + arow) * GKP;
    bool arok = (gr < NGENE);
    f32x4 acc[4][4] = {};

    float av[16];
    uint4 rbh0, rbh1, rbl0, rbl1;
    {
        int gk = kbeg + akp;
        #pragma unroll
        for (int j = 0; j < 16; j += 4) {
            float4 v = (arok && gk + j < NGENE) ? *(const float4*)(arowp + gk + j)
                                                : make_float4(0.f, 0.f, 0.f, 0.f);
            av[j] = v.x; av[j + 1] = v.y; av[j + 2] = v.z; av[j + 3] = v.w;
        }
        rbh0 = *(const uint4*)(bhp + gk); rbh1 = *(const uint4*)(bhp + gk + 8);
        rbl0 = *(const uint4*)(blp + gk); rbl1 = *(const uint4*)(blp + gk + 8);
    }
    {
        unsigned short ah[16], alr[16];
        #pragma unroll
        for (int j = 0; j < 16; ++j) {
            unsigned u = __float_as_uint(av[j]);
            ah[j] = (unsigned short)(u >> 16);
            alr[j] = f2bf(av[j] - __uint_as_float(u & 0xffff0000u));
        }
        char* AsH = lds; char* AsL = lds + 8192;
        char* BsH = lds + 16384; char* BsL = lds + 24576;
        *(uint4*)(AsH + wo0) = *(const uint4*)&ah[0];
        *(uint4*)(AsH + wo1) = *(const uint4*)&ah[8];
        *(uint4*)(AsL + wo0) = *(const uint4*)&alr[0];
        *(uint4*)(AsL + wo1) = *(const uint4*)&alr[8];
        *(uint4*)(BsH + wo0) = rbh0; *(uint4*)(BsH + wo1) = rbh1;
        *(uint4*)(BsL + wo0) = rbl0; *(uint4*)(BsL + wo1) = rbl1;
    }
    __syncthreads();
    for (int i = 0; i < niter; ++i) {
        bool more = (i + 1 < niter);
        if (more) {
            int gk = kbeg + (i + 1) * 32 + akp;
            #pragma unroll
            for (int j = 0; j < 16; j += 4) {
                float4 v = (arok && gk + j < NGENE) ? *(const float4*)(arowp + gk + j)
                                                    : make_float4(0.f, 0.f, 0.f, 0.f);
                av[j] = v.x; av[j + 1] = v.y; av[j + 2] = v.z; av[j + 3] = v.w;
            }
            rbh0 = *(const uint4*)(bhp + gk); rbh1 = *(const uint4*)(bhp + gk + 8);
            rbl0 = *(const uint4*)(blp + gk); rbl1 = *(const uint4*)(blp + gk + 8);
        }
        {
            char* base = lds + (i & 1) * 32768;
            char* AsH = base; char* AsL = base + 8192;
            char* BsH = base + 16384; char* BsL = base + 24576;
            bf16x8 afh[4], afl[4], bfh[4], bfl[4];
            #pragma unroll
            for (int m = 0; m < 4; ++m) {
                int Bb = (wr * 64 + m * 16 + r16) * 64 + soA;
                afh[m] = *(const bf16x8*)(AsH + Bb);
                afl[m] = *(const bf16x8*)(AsL + Bb);
            }
            #pragma unroll
            for (int n = 0; n < 4; ++n) {
                int Bb = (wc * 64 + n * 16 + r16) * 64 + soA;
                bfh[n] = *(const bf16x8*)(BsH + Bb);
                bfl[n] = *(const bf16x8*)(BsL + Bb);
            }
            #pragma unroll
            for (int m = 0; m < 4; ++m)
                #pragma unroll
                for (int n = 0; n < 4; ++n) {
                    acc[m][n] = __builtin_amdgcn_mfma_f32_16x16x32_bf16(afh[m], bfh[n], acc[m][n], 0, 0, 0);
                    acc[m][n] = __builtin_amdgcn_mfma_f32_16x16x32_bf16(afh[m], bfl[n], acc[m][n], 0, 0, 0);
                    acc[m][n] = __builtin_amdgcn_mfma_f32_16x16x32_bf16(afl[m], bfh[n], acc[m][n], 0, 0, 0);
                }
        }
        if (more) {
            unsigned short ah[16], alr[16];
            #pragma unroll
            for (int j = 0; j < 16; ++j) {
                unsigned u = __float_as_uint(av[j]);
                ah[j] = (unsigned short)(u >> 16);
                alr[j] = f2bf(av[j] - __uint_as_float(u & 0xffff0000u));
            }
            char* base = lds + ((i + 1) & 1) * 32768;
            char* AsH = base; char* AsL = base + 8192;
            char* BsH = base + 16384; char* BsL = base + 24576;
            *(uint4*)(AsH + wo0) = *(const uint4*)&ah[0];
            *(uint4*)(AsH + wo1) = *(const uint4*)&ah[8];
            *(uint4*)(AsL + wo0) = *(const uint4*)&alr[0];
            *(uint4*)(AsL + wo1) = *(const uint4*)&alr[8];
            *(uint4*)(BsH + wo0) = rbh0; *(uint4*)(BsH + wo1) = rbh1;
            *(uint4*)(BsL + wo0) = rbl0; *(uint4*)(BsL + wo1) = rbl1;
        }
        __syncthreads();
    }
    #pragma unroll
    for (int m = 0; m < 4; ++m) {
        #pragma unroll
        for (int n = 0; n < 4; ++n) {
            #pragma unroll
            for (int r = 0; r < 4; ++r) {
                int rowg = row0 + wr * 64 + m * 16 + g * 4 + r;
                int colg = col0 + wc * 64 + n * 16 + r16;
                if (rowg < NGENE)
                    part[((long)z * NGENE + rowg) * H1 + colg] = acc[m][n][r];
            }
        }
    }
}

// ---------------- split-K reduce ----------------
__global__ __launch_bounds__(256) void reduce_splitk_kernel(const float* __restrict__ part,
                                                            const float* __restrict__ bias,
                                                            unsigned short* __restrict__ xh,
                                                            unsigned short* __restrict__ xl)
{
    const long NEL = (long)NGENE * H1;
    long stride = (long)gridDim.x * blockDim.x;
    for (long q = (long)blockIdx.x * blockDim.x + threadIdx.x; q * 4 < NEL; q += stride) {
        long e = q * 4;
        float4 sv = *(const float4*)(part + e);
        #pragma unroll
        for (int z = 1; z < ZSPLIT; ++z) {
            float4 t = *(const float4*)(part + (long)z * NEL + e);
            sv.x += t.x; sv.y += t.y; sv.z += t.z; sv.w += t.w;
        }
        int col = (int)(e & (H1 - 1));
        float4 b = *(const float4*)(bias + col);
        float v[4] = {sv.x + b.x, sv.y + b.y, sv.z + b.z, sv.w + b.w};
        unsigned short oh[4], ol[4];
        #pragma unroll
        for (int i = 0; i < 4; ++i) {
            oh[i] = f2bf(v[i]);
            ol[i] = f2bf(v[i] - bf2f(oh[i]));
        }
        long o = (long)(NDRUG + NCELL) * H1 + e;
        *(uint2*)(xh + o) = *(const uint2*)oh;
        *(uint2*)(xl + o) = *(const uint2*)ol;
    }
}

// ---------------- init1: shallow-grid fixed (500 blocks, stride) ----------------
__global__ void init1_kernel(float* m, int* deg, float* colstats, float* scal)
{
    int stride = gridDim.x * 256;
    for (int i = blockIdx.x * 256 + threadIdx.x; i < NNODE * 4; i += stride) {
        m[i] = -3.402823466e38f;
        if (i < NNODE) deg[i] = 0;
        if (i < 1024) colstats[i] = 0.f;
        if (i < 8) scal[i] = 0.f;
    }
}

// ---------------- fused: degree histogram + sum(edge_attr) + ce ----------------
#define DEG_BLKS 657
__global__ __launch_bounds__(512) void deg_pre_kernel(const int* __restrict__ ei,
                                                      int* __restrict__ deg,
                                                      const float* __restrict__ eattr, float* scal,
                                                      const float* We1, const float* ae1,
                                                      const float* We2, const float* ae2, float* ce)
{
    int b = blockIdx.x;
    if (b < DEG_BLKS) {
        // degree histogram: 657 blocks x 256 edges (use lower 256 threads)
        if (threadIdx.x < 256) {
            int e = b * 256 + threadIdx.x;
            if (e < ET) {
                int d = (e < E0) ? ei[E0 + e] : (e - E0);
                atomicAdd(&deg[d], 1);
            }
        }
    } else if (b < DEG_BLKS + 64) {
        float s = 0.f;
        for (int i = (b - DEG_BLKS) * 512 + threadIdx.x; i < E0; i += 64 * 512)
            s += eattr[i];
        for (int off = 32; off; off >>= 1) s += __shfl_down(s, off);
        if ((threadIdx.x & 63) == 0) atomicAdd(&scal[0], s);
    } else {
        __shared__ float sm[512];
        int t = threadIdx.x;
        sm[t] = We1[t] * ae1[t];
        __syncthreads();
        if (t < 4) { float s = 0.f; for (int c = 0; c < 128; ++c) s += sm[t * 128 + c]; ce[t] = s; }
        __syncthreads();
        sm[t] = We2[t] * ae2[t];
        __syncthreads();
        if (t < 4) { float s = 0.f; for (int c = 0; c < 128; ++c) s += sm[t * 128 + c]; ce[4 + t] = s; }
    }
}

// ---------------- exclusive scan ----------------
__global__ __launch_bounds__(1024) void scan_kernel(const int* __restrict__ deg,
                                                    int* __restrict__ row_start,
                                                    int* __restrict__ cursor)
{
    __shared__ int sm[1024];
    int t = threadIdx.x;
    int base = t * 8;
    int loc[8];
    int sum = 0;
    #pragma unroll
    for (int j = 0; j < 8; ++j) {
        int v = (base + j < NNODE) ? deg[base + j] : 0;
        loc[j] = sum; sum += v;
    }
    sm[t] = sum;
    __syncthreads();
    for (int off = 1; off < 1024; off <<= 1) {
        int v = (t >= off) ? sm[t - off] : 0;
        __syncthreads();
        sm[t] += v;
        __syncthreads();
    }
    int excl = sm[t] - sum;
    #pragma unroll
    for (int j = 0; j < 8; ++j) {
        int idx = base + j;
        if (idx < NNODE) { int v = excl + loc[j]; row_start[idx] = v; cursor[idx] = v; }
    }
    if (t == 1023) row_start[NNODE] = sm[1023];
}

// ---------------- scatter edge structure into CSR ----------------
__global__ void scatter_csr_kernel(const int* __restrict__ ei, int* __restrict__ cursor,
                                   int* __restrict__ csr_src, int* __restrict__ pos_of_e)
{
    int e = blockIdx.x * blockDim.x + threadIdx.x;
    if (e >= ET) return;
    int s, d;
    if (e < E0) { s = ei[e]; d = ei[E0 + e]; }
    else        { s = d = e - E0; }
    int pos = atomicAdd(&cursor[d], 1);
    csr_src[pos] = s;
    pos_of_e[e] = pos;
}

// ---------------- per-node attention coefficients (4 nodes per block) ----------------
// INIT2: extra block (blockIdx.x == NNODE/4) re-inits mbuf (-inf) and colsum+colsq (zeros)
// for layer 2 -- consumed by the NEXT kernels (alpha_max2 / colstats2), ordered by kernel boundary.
template<int INIT2>
__global__ __launch_bounds__(256) void attn_coef_kernel(const float* __restrict__ xw,
                                                        const float* __restrict__ as,
                                                        const float* __restrict__ ad,
                                                        float* __restrict__ a_src,
                                                        float* __restrict__ a_dst,
                                                        float* __restrict__ mbuf,
                                                        float* __restrict__ colstats)
{
    if (INIT2 && blockIdx.x == NNODE / 4) {
        for (int i = threadIdx.x; i < NNODE * 4; i += 256)
            mbuf[i] = -3.402823466e38f;
        for (int i = threadIdx.x; i < 1024; i += 256)
            colstats[i] = 0.f;
        return;
    }
    int n = blockIdx.x * 4 + (threadIdx.x >> 6);
    int l = threadIdx.x & 63;
    #pragma unroll
    for (int h = 0; h < 4; ++h) {
        float x1 = xw[(long)n * HD + h * 128 + l];
        float x2 = xw[(long)n * HD + h * 128 + 64 + l];
        float s = x1 * as[h * 128 + l] + x2 * as[h * 128 + 64 + l];
        float d = x1 * ad[h * 128 + l] + x2 * ad[h * 128 + 64 + l];
        for (int off = 32; off; off >>= 1) { s += __shfl_down(s, off); d += __shfl_down(d, off); }
        if (l == 0) { a_src[n * 4 + h] = s; a_dst[n * 4 + h] = d; }
    }
}

// ---------------- atomic float max ----------------
__device__ inline void atomicMaxF(float* addr, float v)
{
    if (v >= 0.f) atomicMax((int*)addr, __float_as_int(v));
    else          atomicMin((unsigned int*)addr, __float_as_uint(v));
}

// ---------------- per-edge alpha (scatter to CSR order) + segment max ----------------
__global__ void alpha_max_kernel(const int* __restrict__ ei, const float* __restrict__ eattr,
                                 const float* __restrict__ scal,
                                 const float* __restrict__ a_src, const float* __restrict__ a_dst,
                                 const float* __restrict__ ce,
                                 float* __restrict__ csr_alpha,
                                 const int* __restrict__ pos_of_e,
                                 float* __restrict__ m)
{
    int e = blockIdx.x * blockDim.x + threadIdx.x;
    if (e >= ET) return;
    int s, d; float a;
    if (e < E0) { s = ei[e]; d = ei[E0 + e]; a = eattr[e]; }
    else        { s = d = e - E0; a = scal[0] * (1.0f / E0); }
    float4 av;
    float* avp = (float*)&av;
    #pragma unroll
    for (int h = 0; h < 4; ++h) {
        float v = a_src[s * 4 + h] + a_dst[d * 4 + h] + a * ce[h];
        v = v > 0.f ? v : 0.2f * v;
        avp[h] = v;
        atomicMaxF(&m[d * 4 + h], v);
    }
    *(float4*)(csr_alpha + (long)pos_of_e[e] * 4) = av;
}

// ---------------- aggregation ----------------
__global__ __launch_bounds__(256) void aggregate_kernel(const unsigned short* __restrict__ xwb,
                                                        const float* __restrict__ csr_alpha,
                                                        const float* __restrict__ m,
                                                        const int* __restrict__ rs,
                                                        const int* __restrict__ csr_src,
                                                        const float* __restrict__ bias,
                                                        float* __restrict__ out)
{
    int n = blockIdx.x;
    int h = threadIdx.x >> 6;
    int l = threadIdx.x & 63;
    float mnh = m[n * 4 + h];
    int i0 = rs[n], i1 = rs[n + 1];
    float den = 0.f;
    for (int i = i0 + l; i < i1; i += 64)
        den += expf(csr_alpha[(long)i * 4 + h] - mnh);
    for (int off = 32; off; off >>= 1) den += __shfl_down(den, off);
    den = __shfl(den, 0);
    float rden = 1.0f / (den + 1e-16f);
    float acc0 = 0.f, acc1 = 0.f;
    int i = i0;
    for (; i + 7 < i1; i += 8) {
        int      sv[8];
        float    av[8];
        unsigned xv[8];
        #pragma unroll
        for (int j = 0; j < 8; ++j) {
            sv[j] = csr_src[i + j];
            av[j] = csr_alpha[(long)(i + j) * 4 + h];
        }
        #pragma unroll
        for (int j = 0; j < 8; ++j)
            xv[j] = *(const unsigned*)(xwb + (long)sv[j] * HD + h * 128 + 2 * l);
        #pragma unroll
        for (int j = 0; j < 8; ++j) {
            float w = expf(av[j] - mnh);
            acc0 += w * bf2f((unsigned short)(xv[j] & 0xffffu));
            acc1 += w * bf2f((unsigned short)(xv[j] >> 16));
        }
    }
    for (; i < i1; ++i) {
        int s = csr_src[i];
        float w = expf(csr_alpha[(long)i * 4 + h] - mnh);
        unsigned x = *(const unsigned*)(xwb + (long)s * HD + h * 128 + 2 * l);
        acc0 += w * bf2f((unsigned short)(x & 0xffffu));
        acc1 += w * bf2f((unsigned short)(x >> 16));
    }
    float2 o;
    o.x = acc0 * rden + bias[h * 128 + 2 * l];
    o.y = acc1 * rden + bias[h * 128 + 2 * l + 1];
    *(float2*)(out + (long)n * HD + h * 128 + 2 * l) = o;
}

// ---------------- graph norm: fused column sum + sum-of-squares ----------------
__global__ __launch_bounds__(256) void colstats_kernel(const float* __restrict__ x,
                                                       float* __restrict__ colsum,
                                                       float* __restrict__ colsumsq)
{
    int t = threadIdx.x, b = blockIdx.x;
    float s0 = 0.f, s1 = 0.f, q0 = 0.f, q1 = 0.f;
    int r0 = b * 32, r1e = r0 + 32;
    for (int r = r0; r < r1e; ++r) {
        float v0 = x[(long)r * HD + t];
        float v1 = x[(long)r * HD + t + 256];
        s0 += v0; q0 += v0 * v0;
        s1 += v1; q1 += v1 * v1;
    }
    atomicAdd(&colsum[t], s0);
    atomicAdd(&colsum[t + 256], s1);
    atomicAdd(&colsumsq[t], q0);
    atomicAdd(&colsumsq[t + 256], q1);
}

// norm (+ReLU) in place; writes hi/lo bf16 copies
__global__ void norm_kernel(float* __restrict__ x,
                            unsigned short* __restrict__ xbh, unsigned short* __restrict__ xbl,
                            const float* __restrict__ colsum,
                            const float* __restrict__ colsumsq,
                            const float* __restrict__ g, const float* __restrict__ be,
                            const float* __restrict__ ms)
{
    int stride = gridDim.x * blockDim.x;
    for (int idx = blockIdx.x * blockDim.x + threadIdx.x; idx < NNODE * HD; idx += stride) {
        int j = idx & 511;
        float mu  = colsum[j] * (1.0f / NNODE);
        float ex2 = colsumsq[j] * (1.0f / NNODE);
        float msj = ms[j];
        float var = ex2 - msj * (2.0f - msj) * mu * mu;
        float v = x[idx] - msj * mu;
        float y = g[j] * v / sqrtf(var + 1e-5f) + be[j];
        y = y > 0.f ? y : 0.f;
        x[idx] = y;
        unsigned short h = f2bf(y);
        xbh[idx] = h;
        xbl[idx] = f2bf(y - bf2f(h));
    }
}

// ---------------- prediction head ----------------
__global__ __launch_bounds__(256) void head_kernel(const float* __restrict__ x2,
                                                   const int* __restrict__ idd,
                                                   const int* __restrict__ idc,
                                                   const float* __restrict__ Wout,
                                                   const float* __restrict__ bout,
                                                   float* __restrict__ out0)
{
    int w = threadIdx.x >> 6, l = threadIdx.x & 63;
    int b = blockIdx.x * 4 + w;
    if (b >= BSZ) return;
    int rd = idd[b], rc = idc[b];
    float s = 0.f;
    #pragma unroll
    for (int k = l; k < HD; k += 64)
        s += x2[(long)rd * HD + k] * Wout[k] + x2[(long)rc * HD + k] * Wout[HD + k];
    for (int off = 32; off; off >>= 1) s += __shfl_down(s, off);
    if (l == 0) out0[b] = s + bout[0];
}

// ---------------- all_att: zero + scatter scalar ----------------
__global__ void zero_f4_kernel(float4* __restrict__ p, long n4)
{
    long stride = (long)gridDim.x * blockDim.x;
    for (long i = (long)blockIdx.x * blockDim.x + threadIdx.x; i < n4; i += stride)
        p[i] = make_float4(0.f, 0.f, 0.f, 0.f);
}

__global__ void scatter_att_kernel(const int* __restrict__ ei, float* __restrict__ attm)
{
    int e = blockIdx.x * blockDim.x + threadIdx.x;
    if (e >= ET) return;
    int s, d;
    if (e < E0) { s = ei[e]; d = ei[E0 + e]; }
    else        { s = d = e - E0; }
    const float val = 2.0f * (float)NNODE / (float)ET;
    attm[(long)s * NNODE + d] = val;
}

// ---------------- launch ----------------
extern "C" void kernel_launch(void* const* d_in, const int* in_sizes, int n_in,
                              void* d_out, int out_size, void* d_ws, size_t ws_size,
                              hipStream_t stream)
{
    const float* drug   = (const float*)d_in[0];
    const float* cell   = (const float*)d_in[1];
    const float* gene   = (const float*)d_in[2];
    const float* eattr  = (const float*)d_in[3];
    const int*   ei     = (const int*)d_in[4];
    const int*   idd    = (const int*)d_in[5];
    const int*   idc    = (const int*)d_in[6];
    const float* Wdrug  = (const float*)d_in[7];
    const float* bdrug  = (const float*)d_in[8];
    const float* Wcell  = (const float*)d_in[9];
    const float* bcell  = (const float*)d_in[10];
    const float* Wgene  = (const float*)d_in[11];
    const float* bgene  = (const float*)d_in[12];
    const float* W1     = (const float*)d_in[13];
    const float* b1     = (const float*)d_in[14];
    const float* as1    = (const float*)d_in[15];
    const float* ad1    = (const float*)d_in[16];
    const float* We1    = (const float*)d_in[17];
    const float* ae1    = (const float*)d_in[18];
    const float* bias1  = (const float*)d_in[19];
    const float* g1     = (const float*)d_in[20];
    const float* be1    = (const float*)d_in[21];
    const float* ms1    = (const float*)d_in[22];
    const float* W2     = (const float*)d_in[23];
    const float* b2     = (const float*)d_in[24];
    const float* as2    = (const float*)d_in[25];
    const float* ad2    = (const float*)d_in[26];
    const float* We2    = (const float*)d_in[27];
    const float* ae2    = (const float*)d_in[28];
    const float* bias2  = (const float*)d_in[29];
    const float* g2     = (const float*)d_in[30];
    const float* be2    = (const float*)d_in[31];
    const float* ms2    = (const float*)d_in[32];
    const float* Wout   = (const float*)d_in[33];
    const float* bout   = (const float*)d_in[34];

    float* out0 = (float*)d_out;                 // [10000]
    float* attm = (float*)d_out + BSZ;           // [8000*8000]

    // ---- workspace layout ----
    float* ws     = (float*)d_ws;
    float* xw     = ws;                          // 8000*512
    float* outb   = xw + (long)NNODE * HD;       // 8000*512
    float* csr_al = outb + (long)NNODE * HD;     // 168000*4
    float* a_src  = csr_al + (long)ET * 4;       // 32000
    float* a_dst  = a_src + NNODE * 4;           // 32000
    float* mbuf   = a_dst + NNODE * 4;           // 32000
    float* colsum = mbuf + NNODE * 4;            // 512
    float* colsq  = colsum + 512;                // 512
    float* ce     = colsq + 512;                 // 8
    float* scal   = ce + 8;                      // 8
    int* deg      = (int*)(scal + 8);            // 8000
    int* rs       = deg + NNODE;                 // 8004
    int* cursor   = rs + NNODE + 4;              // 8000
    int* csr_src  = cursor + NNODE;              // 168000
    int* pos_of_e = csr_src + ET;                // 168000
    unsigned short* p = (unsigned short*)(pos_of_e + ET);
    unsigned short* xwb    = p; p += (long)NNODE * HD;
    unsigned short* drug_h = p; p += (long)1024 * 1024;
    unsigned short* drug_l = p; p += (long)1024 * 1024;
    unsigned short* cell_h = p; p += (long)1024 * 1024;
    unsigned short* cell_l = p; p += (long)1024 * 1024;
    unsigned short* x0_h   = p; p += (long)NNODE * H1;
    unsigned short* x0_l   = p; p += (long)NNODE * H1;
    unsigned short* xb_h   = p; p += (long)NNODE * HD;
    unsigned short* xb_l   = p; p += (long)NNODE * HD;
    unsigned short* Wd_h   = p; p += 256 * 1024;
    unsigned short* Wd_l   = p; p += 256 * 1024;
    unsigned short* Wc_h   = p; p += 256 * 1024;
    unsigned short* Wc_l   = p; p += 256 * 1024;
    unsigned short* Wg_h   = p; p += 256 * GKP;
    unsigned short* Wg_l   = p; p += 256 * GKP;
    unsigned short* W1_h   = p; p += 512 * 256;
    unsigned short* W1_l   = p; p += 512 * 256;
    unsigned short* W2_h   = p; p += 512 * 512;
    unsigned short* W2_l   = p; p += 512 * 512;
    float* partsk = (float*)((((unsigned long long)p) + 15) & ~15ULL);

    dim3 blk256(256);
    int gE = (ET + 255) / 256;

    // init + CSR build + small precomputes (fused)
    init1_kernel<<<500, blk256, 0, stream>>>(mbuf, deg, colsum, scal);
    deg_pre_kernel<<<DEG_BLKS + 65, 512, 0, stream>>>(ei, deg, eattr, scal, We1, ae1, We2, ae2, ce);
    scan_kernel<<<1, 1024, 0, stream>>>(deg, rs, cursor);
    scatter_csr_kernel<<<gE, blk256, 0, stream>>>(ei, cursor, csr_src, pos_of_e);

    // ---- conversions ----
    cvt_pad2_dc_kernel<<<1024, blk256, 0, stream>>>(drug, drug_h, drug_l, cell, cell_h, cell_l);
    {
        TC5 d;
        d.W[0] = Wdrug; d.Wh[0] = Wd_h; d.Wl[0] = Wd_l; d.K[0] = NDRUG; d.N[0] = H1; d.Kp[0] = 1024; d.gx[0] = 32;
        d.W[1] = Wcell; d.Wh[1] = Wc_h; d.Wl[1] = Wc_l; d.K[1] = NCELL; d.N[1] = H1; d.Kp[1] = 1024; d.gx[1] = 32;
        d.W[2] = Wgene; d.Wh[2] = Wg_h; d.Wl[2] = Wg_l; d.K[2] = NGENE; d.N[2] = H1; d.Kp[2] = GKP;  d.gx[2] = 188;
        d.W[3] = W1;    d.Wh[3] = W1_h; d.Wl[3] = W1_l; d.K[3] = H1;    d.N[3] = HD; d.Kp[3] = H1;   d.gx[3] = 8;
        d.W[4] = W2;    d.Wh[4] = W2_h; d.Wl[4] = W2_l; d.K[4] = HD;    d.N[4] = HD; d.Kp[4] = HD;   d.gx[4] = 16;
        d.start[0] = 0;    d.start[1] = 256;  d.start[2] = 512;
        d.start[3] = 2016; d.start[4] = 2144; d.start[5] = 2400;
        transpose_cvt2_batch<<<2400, blk256, 0, stream>>>(d);
    }

    // ---- input projections -> x0 (hi/lo bf16) ----
    gemm_mfma2<1><<<dim3(H1 / 64, 16), blk256, 0, stream>>>(drug_h, drug_l, Wd_h, Wd_l, bdrug,
        nullptr, x0_h, x0_l, nullptr, NDRUG, 1024, H1);
    gemm_mfma2<1><<<dim3(H1 / 64, 16), blk256, 0, stream>>>(cell_h, cell_l, Wc_h, Wc_l, bcell,
        nullptr, x0_h + (long)NDRUG * H1, x0_l + (long)NDRUG * H1, nullptr, NCELL, 1024, H1);
    gemm_gene_f32<<<752, blk256, 0, stream>>>(gene, Wg_h, Wg_l, partsk);
    reduce_splitk_kernel<<<1500, blk256, 0, stream>>>(partsk, bgene, x0_h, x0_l);

    // ---- layer 1 ----
    gemm_mfma2<0><<<dim3(HD / 64, NNODE / 64), blk256, 0, stream>>>(x0_h, x0_l, W1_h, W1_l, b1,
        xw, nullptr, nullptr, xwb, NNODE, H1, HD);
    attn_coef_kernel<0><<<NNODE / 4, blk256, 0, stream>>>(xw, as1, ad1, a_src, a_dst, nullptr, nullptr);
    alpha_max_kernel<<<gE, blk256, 0, stream>>>(ei, eattr, scal, a_src, a_dst, ce,
        csr_al, pos_of_e, mbuf);
    aggregate_kernel<<<NNODE, blk256, 0, stream>>>(xwb, csr_al, mbuf, rs, csr_src, bias1, outb);
    colstats_kernel<<<250, blk256, 0, stream>>>(outb, colsum, colsq);
    norm_kernel<<<2048, blk256, 0, stream>>>(outb, xb_h, xb_l, colsum, colsq, g1, be1, ms1);

    // ---- layer 2 ----
    gemm_mfma2<0><<<dim3(HD / 64, NNODE / 64), blk256, 0, stream>>>(xb_h, xb_l, W2_h, W2_l, b2,
        xw, nullptr, nullptr, xwb, NNODE, HD, HD);
    attn_coef_kernel<1><<<NNODE / 4 + 1, blk256, 0, stream>>>(xw, as2, ad2, a_src, a_dst, mbuf, colsum);
    alpha_max_kernel<<<gE, blk256, 0, stream>>>(ei, eattr, scal, a_src, a_dst, ce + 4,
        csr_al, pos_of_e, mbuf);
    aggregate_kernel<<<NNODE, blk256, 0, stream>>>(xwb, csr_al, mbuf, rs, csr_src, bias2, outb);
    colstats_kernel<<<250, blk256, 0, stream>>>(outb, colsum, colsq);
    norm_kernel<<<2048, blk256, 0, stream>>>(outb, xb_h, xb_l, colsum, colsq, g2, be2, ms2);

    // ---- head + attention matrix ----
    head_kernel<<<(BSZ + 3) / 4, blk256, 0, stream>>>(outb, idd, idc, Wout, bout, out0);
    zero_f4_kernel<<<2048, blk256, 0, stream>>>((float4*)attm, (long)NNODE * NNODE / 4);
    scatter_att_kernel<<<gE, blk256, 0, stream>>>(ei, attm);
}